// Round 12
// baseline (2017.951 us; speedup 1.0000x reference)
//
#include <hip/hip_runtime.h>
#include <cstddef>
#include <cstdint>

#define LANG 50257
#define EDIM 512
#define HDIM 1024
#define ADIM 512
#define SLEN 1024
#define NSTEP 25
#define TEMPF 10.0f
#define SOSIDX 1
#define VOFF (NSTEP * LANG)
#define NBLK 256
#define NTHR 1024

// ---- ws byte offsets --------------------------------------------------------
#define OFF_W8     0u           // int8 out_W, permuted rows: 53248*1536
#define OFF_SCL    81788928u    // fp32 per-row scale, 53248
#define OFF_EMBTB  82001920u    // int8 emb_T rows: 50257*512 (region sized 51MB)
#define OFF_P      133465088u   // fp32 P[s][a] 1024*512
#define OFF_H      135562240u   // 2*1024
#define OFF_HPROJ8 135570432u   // 8*512
#define OFF_EANX8  135586816u   // 8*512
#define OFF_ATTN8  135603200u   // 8*512
#define OFF_DENWP  135619584u   // 256
#define OFF_SDENP  135620608u   // 256
#define OFF_BAR    135622656u   // flags[256]+gfl[16]+go (memset per launch)
#define OFF_ESCL   135627776u   // fp32 per-row emb scale, 50257

__device__ __forceinline__ float wred(float x) {
#pragma unroll
  for (int off = 32; off; off >>= 1) x += __shfl_down(x, off);
  return x;
}

// device-scope (coherence-point) accesses, NO cache maintenance
__device__ __forceinline__ unsigned gldu(const unsigned* p) {
  return __hip_atomic_load((unsigned*)p, __ATOMIC_RELAXED, __HIP_MEMORY_SCOPE_AGENT);
}
__device__ __forceinline__ void gstu(unsigned* p, unsigned v) {
  __hip_atomic_store(p, v, __ATOMIC_RELAXED, __HIP_MEMORY_SCOPE_AGENT);
}
__device__ __forceinline__ float gldf(const float* p) {
  return __hip_atomic_load((float*)p, __ATOMIC_RELAXED, __HIP_MEMORY_SCOPE_AGENT);
}
__device__ __forceinline__ void gstf(float* p, float v) {
  __hip_atomic_store(p, v, __ATOMIC_RELAXED, __HIP_MEMORY_SCOPE_AGENT);
}

// Fence-free tree barrier: relaxed device-scope flags (R8, proven).
__device__ __forceinline__ void gridbar(unsigned* bar, int bid, unsigned round) {
  __syncthreads();
  const int tid = threadIdx.x;
  asm volatile("" ::: "memory");
  if (tid < 64) {
    if (tid == 0) {
      asm volatile("s_waitcnt vmcnt(0) lgkmcnt(0)" ::: "memory");
      gstu(&bar[bid], round);
    }
    if ((bid & 15) == 0) {
      unsigned v;
      do { v = (tid < 16) ? gldu(&bar[bid + tid]) : round; } while (__any(v < round));
      if (tid == 0) gstu(&bar[256 + (bid >> 4)], round);
    }
    if (bid == 0) {
      unsigned v;
      do { v = (tid < 16) ? gldu(&bar[256 + tid]) : round; } while (__any(v < round));
      if (tid == 0) gstu(&bar[272], round);
    }
    if (tid == 0) {
      while (gldu(&bar[272]) < round) __builtin_amdgcn_s_sleep(1);
    }
  }
  asm volatile("" ::: "memory");
  __syncthreads();
}

__device__ __forceinline__ void gridbar_f(unsigned* bar, int bid, unsigned round) {
  __syncthreads();
  if (threadIdx.x == 0) __threadfence();
  gridbar(bar, bid, round);
  if (threadIdx.x == 0) __threadfence();
  __syncthreads();
}

// int8 dot helpers: byte j of row = column j (identity layout)
#define DOTW(w, x0, x1, x2, x3)                                          \
  {                                                                      \
    acc += (float)((int)((w) << 24) >> 24) * (x0);                       \
    acc += (float)((int)((w) << 16) >> 24) * (x1);                       \
    acc += (float)((int)((w) << 8)  >> 24) * (x2);                       \
    acc += (float)((int)(w) >> 24)          * (x3);                      \
  }

__global__ __launch_bounds__(NTHR, 4) void k_decoder(
    const float* __restrict__ hidden, const float* __restrict__ emb_src,
    const float* __restrict__ emb_T,  const float* __restrict__ W_ih,
    const float* __restrict__ W_hh,   const float* __restrict__ b_ih,
    const float* __restrict__ b_hh,   const float* __restrict__ W1,
    const float* __restrict__ b1,     const float* __restrict__ vvec,
    const float* __restrict__ out_W,  const float* __restrict__ out_b,
    float* __restrict__ out, char* __restrict__ wsb) {
  __shared__ __align__(16) float smem[9776];
  const int tid = threadIdx.x, bid = blockIdx.x;
  const int wid = tid >> 6, lane = tid & 63;

  float* P      = (float*)(wsb + OFF_P);
  float* hws    = (float*)(wsb + OFF_H);
  float* hproj8 = (float*)(wsb + OFF_HPROJ8);
  float* eanx8  = (float*)(wsb + OFF_EANX8);
  float* attn8  = (float*)(wsb + OFF_ATTN8);
  float* denwp  = (float*)(wsb + OFF_DENWP);
  float* sdenp  = (float*)(wsb + OFF_SDENP);
  float* scl    = (float*)(wsb + OFF_SCL);
  float* escl   = (float*)(wsb + OFF_ESCL);
  unsigned* bar = (unsigned*)(wsb + OFF_BAR);
  unsigned rnd = 0;

  // ================= pre-phase ==============================================
  {
    // out_W -> int8 per-row scale, owner-permuted (wave gw owns l=gw+r*4096
    // at p=gw*13+r); tail rows zero-filled for unconditional pipelined loads.
    uint2* w8w = (uint2*)(wsb + OFF_W8);
    const float4* src = (const float4*)out_W;
    int gw = bid * 16 + wid;
    for (int r = 0; r < 13; ++r) {
      int l = gw + r * 4096;
      if (r < 12 || l < LANG) {
        int p = gw * 13 + r;
        float4 f[6];
#pragma unroll
        for (int k = 0; k < 3; ++k) {
          f[2 * k]     = src[(size_t)l * 384 + k * 128 + lane * 2];
          f[2 * k + 1] = src[(size_t)l * 384 + k * 128 + lane * 2 + 1];
        }
        float mx = 0.f;
#pragma unroll
        for (int k = 0; k < 6; ++k)
          mx = fmaxf(mx, fmaxf(fmaxf(fabsf(f[k].x), fabsf(f[k].y)),
                               fmaxf(fabsf(f[k].z), fabsf(f[k].w))));
#pragma unroll
        for (int off = 32; off; off >>= 1) mx = fmaxf(mx, __shfl_down(mx, off));
        mx = __shfl(mx, 0);
        float inv = (mx > 0.f) ? 127.f / mx : 0.f;
#pragma unroll
        for (int k = 0; k < 3; ++k) {
          unsigned ux = 0, uy = 0;
          ux |= ((unsigned)((int)rintf(f[2*k].x * inv) & 255));
          ux |= ((unsigned)((int)rintf(f[2*k].y * inv) & 255)) << 8;
          ux |= ((unsigned)((int)rintf(f[2*k].z * inv) & 255)) << 16;
          ux |= ((unsigned)((int)rintf(f[2*k].w * inv) & 255)) << 24;
          uy |= ((unsigned)((int)rintf(f[2*k+1].x * inv) & 255));
          uy |= ((unsigned)((int)rintf(f[2*k+1].y * inv) & 255)) << 8;
          uy |= ((unsigned)((int)rintf(f[2*k+1].z * inv) & 255)) << 16;
          uy |= ((unsigned)((int)rintf(f[2*k+1].w * inv) & 255)) << 24;
          w8w[(size_t)p * 192 + k * 64 + lane] = make_uint2(ux, uy);
        }
        if (lane == 0) scl[p] = (mx > 0.f) ? mx / 127.f : 0.f;
      } else {
        int p = gw * 13 + r;
#pragma unroll
        for (int k = 0; k < 3; ++k)
          w8w[(size_t)p * 192 + k * 64 + lane] = make_uint2(0u, 0u);
        if (lane == 0) scl[p] = 0.f;
      }
    }
    // emb_T -> int8 per-row scale (row l: lane holds dims 8*lane..8*lane+7)
    {
      uint2* e8w = (uint2*)(wsb + OFF_EMBTB);
      for (int l = gw; l < LANG; l += 4096) {
        const float4* er = (const float4*)(emb_T + (size_t)l * 512);
        float4 f0 = er[lane * 2], f1 = er[lane * 2 + 1];
        float mx = fmaxf(fmaxf(fmaxf(fabsf(f0.x), fabsf(f0.y)),
                               fmaxf(fabsf(f0.z), fabsf(f0.w))),
                         fmaxf(fmaxf(fabsf(f1.x), fabsf(f1.y)),
                               fmaxf(fabsf(f1.z), fabsf(f1.w))));
#pragma unroll
        for (int off = 32; off; off >>= 1) mx = fmaxf(mx, __shfl_down(mx, off));
        mx = __shfl(mx, 0);
        float inv = (mx > 0.f) ? 127.f / mx : 0.f;
        unsigned ux = 0, uy = 0;
        ux |= ((unsigned)((int)rintf(f0.x * inv) & 255));
        ux |= ((unsigned)((int)rintf(f0.y * inv) & 255)) << 8;
        ux |= ((unsigned)((int)rintf(f0.z * inv) & 255)) << 16;
        ux |= ((unsigned)((int)rintf(f0.w * inv) & 255)) << 24;
        uy |= ((unsigned)((int)rintf(f1.x * inv) & 255));
        uy |= ((unsigned)((int)rintf(f1.y * inv) & 255)) << 8;
        uy |= ((unsigned)((int)rintf(f1.z * inv) & 255)) << 16;
        uy |= ((unsigned)((int)rintf(f1.w * inv) & 255)) << 24;
        e8w[(size_t)l * 64 + lane] = make_uint2(ux, uy);
        if (lane == 0) escl[l] = (mx > 0.f) ? mx / 127.f : 0.f;
      }
    }
    // P = emb_src @ W1[:A] + b1  (4 src rows per block)
    for (int i = tid; i < 4 * ADIM; i += NTHR)
      smem[i] = emb_src[(size_t)bid * 4 * ADIM + i];
    __syncthreads();
    if (tid < ADIM) {
      int a = tid;
      float bb = b1[a];
      float a0 = bb, a1 = bb, a2 = bb, a3 = bb;
      for (int k = 0; k < ADIM; ++k) {
        float w = W1[(size_t)k * ADIM + a];
        a0 += smem[k] * w; a1 += smem[512 + k] * w;
        a2 += smem[1024 + k] * w; a3 += smem[1536 + k] * w;
      }
      P[(size_t)(bid * 4 + 0) * ADIM + a] = a0;
      P[(size_t)(bid * 4 + 1) * ADIM + a] = a1;
      P[(size_t)(bid * 4 + 2) * ADIM + a] = a2;
      P[(size_t)(bid * 4 + 3) * ADIM + a] = a3;
    }
    if (bid == 0) {
      for (int i = tid; i < 8 * EDIM; i += NTHR)
        eanx8[i] = (i < EDIM) ? emb_T[(size_t)SOSIDX * EDIM + i] : 0.f;
      if (tid < 256) denwp[tid] = (tid == 0) ? 1.0f : 0.0f;
    }
    if (bid == 1) { for (int i = tid; i < 8 * ADIM; i += NTHR) hproj8[i] = 0.f; }
    if (bid == 2) { hws[tid] = hidden[tid]; }
    if (bid == 3) { for (int i = tid; i < 8 * ADIM; i += NTHR) attn8[i] = 0.f; }
  }
  rnd++; gridbar_f(bar, bid, rnd);

  for (int t = 0; t < NSTEP; ++t) {
    const int cur = t & 1, nxt = cur ^ 1;
    float* hold = hws + cur * HDIM;
    float* hnew = hws + nxt * HDIM;

    // ==== X: GRU + hproj scatter (+ zero attn8) =============================
    {
      float easum = 0.f;
      if (tid < EDIM) {
#pragma unroll
        for (int k = 0; k < 8; ++k) easum += gldf(&eanx8[k * EDIM + tid]);
      }
      float dp = 0.f;
      if (tid >= 512 && tid < 768) dp = gldf(&denwp[tid - 512]);
      smem[512 + tid] = gldf(&hold[tid]);
      if (bid < 8 && tid < ADIM) gstf(&attn8[bid * ADIM + tid], 0.f);
      dp = wred(dp);
      if (tid >= 512 && tid < 768 && lane == 0) smem[1632 + (wid - 8)] = dp;
      __syncthreads();
      float inv = 1.0f / (smem[1632] + smem[1633] + smem[1634] + smem[1635]);
      if (tid < EDIM) smem[tid] = easum * inv;
      __syncthreads();

      int jl = wid & 3, part = wid >> 2;
      int j = bid * 4 + jl;
      float ir = 0.f, iz = 0.f, in_ = 0.f;
#pragma unroll
      for (int k = 0; k < 2; ++k) {
        int e = part * 128 + k * 64 + lane;
        float x = smem[e];
        ir  += W_ih[(size_t)j * EDIM + e] * x;
        iz  += W_ih[(size_t)(j + HDIM) * EDIM + e] * x;
        in_ += W_ih[(size_t)(j + 2 * HDIM) * EDIM + e] * x;
      }
      float hr = 0.f, hz = 0.f, hn = 0.f;
#pragma unroll
      for (int k = 0; k < 4; ++k) {
        int e = part * 256 + k * 64 + lane;
        float x = smem[512 + e];
        hr += W_hh[(size_t)j * HDIM + e] * x;
        hz += W_hh[(size_t)(j + HDIM) * HDIM + e] * x;
        hn += W_hh[(size_t)(j + 2 * HDIM) * HDIM + e] * x;
      }
#pragma unroll
      for (int off = 32; off; off >>= 1) {
        ir += __shfl_down(ir, off);  iz += __shfl_down(iz, off);  in_ += __shfl_down(in_, off);
        hr += __shfl_down(hr, off);  hz += __shfl_down(hz, off);  hn += __shfl_down(hn, off);
      }
      if (lane == 0) {
        float* pb = smem + 1536 + (jl * 4 + part) * 6;
        pb[0] = ir; pb[1] = iz; pb[2] = in_; pb[3] = hr; pb[4] = hz; pb[5] = hn;
      }
      __syncthreads();
      if (tid < 4) {
        int jj = bid * 4 + tid;
        float sir = 0.f, siz = 0.f, sin_ = 0.f, shr = 0.f, shz = 0.f, shn = 0.f;
#pragma unroll
        for (int p = 0; p < 4; ++p) {
          float* pb = smem + 1536 + (tid * 4 + p) * 6;
          sir += pb[0]; siz += pb[1]; sin_ += pb[2];
          shr += pb[3]; shz += pb[4]; shn += pb[5];
        }
        float r = 1.f / (1.f + expf(-(sir + b_ih[jj] + shr + b_hh[jj])));
        float z = 1.f / (1.f + expf(-(siz + b_ih[jj + HDIM] + shz + b_hh[jj + HDIM])));
        float n = tanhf(sin_ + b_ih[jj + 2 * HDIM] + r * (shn + b_hh[jj + 2 * HDIM]));
        float hv = (1.f - z) * n + z * smem[512 + jj];
        gstf(&hnew[jj], hv);
        smem[1640 + tid] = hv;
      }
      __syncthreads();
      if (tid < ADIM) {
        float s = 0.f;
#pragma unroll
        for (int jl2 = 0; jl2 < 4; ++jl2)
          s += smem[1640 + jl2] * W1[(size_t)(ADIM + bid * 4 + jl2) * ADIM + tid];
        atomicAdd(&hproj8[(bid & 7) * ADIM + tid], s);
      }
    }
    rnd++; gridbar(bar, bid, rnd);

    // ==== Y: scores + sdenp + attn partials (+ zero eanx8) ==================
    {
      float hp = 0.f;
      if (tid < ADIM) {
#pragma unroll
        for (int k = 0; k < 8; ++k) hp += gldf(&hproj8[k * ADIM + tid]);
      }
      if (tid >= 512) smem[tid] = vvec[tid - 512];
      if (tid < ADIM) smem[tid] = hp;
      if (bid < 8 && tid < EDIM) gstf(&eanx8[bid * EDIM + tid], 0.f);
      __syncthreads();
      int sl = wid & 3, part = wid >> 2;
      int s = bid * 4 + sl;
      float acc = 0.f;
#pragma unroll
      for (int k = 0; k < 2; ++k) {
        int a = part * 128 + k * 64 + lane;
        acc += smem[512 + a] * tanhf(P[(size_t)s * ADIM + a] + smem[a]);
      }
      acc = wred(acc);
      if (lane == 0) smem[1024 + wid] = acc;
      __syncthreads();
      if (tid < 4) {
        float tot = smem[1024 + tid] + smem[1028 + tid] + smem[1032 + tid] + smem[1036 + tid];
        float e = expf(tot);
        smem[1040 + tid] = e;
        smem[9764 + tid] = e;     // persists across barrier for Z's w_out
      }
      __syncthreads();
      if (tid == 0)
        gstf(&sdenp[bid], smem[1040] + smem[1041] + smem[1042] + smem[1043]);
      if (tid < ADIM) {
        float pa = smem[1040] * emb_src[(size_t)(bid * 4 + 0) * ADIM + tid]
                 + smem[1041] * emb_src[(size_t)(bid * 4 + 1) * ADIM + tid]
                 + smem[1042] * emb_src[(size_t)(bid * 4 + 2) * ADIM + tid]
                 + smem[1043] * emb_src[(size_t)(bid * 4 + 3) * ADIM + tid];
        atomicAdd(&attn8[(bid & 7) * ADIM + tid], pa);
      }
    }
    rnd++; gridbar(bar, bid, rnd);

    // ==== Z: fused logits + feedback single-stream pipeline =================
    {
      float sp = 0.f;
      if (tid >= 512 && tid < 768) sp = gldf(&sdenp[tid - 512]);
      smem[tid] = gldf(&hnew[tid]);
      float a8 = 0.f;
      if (tid < ADIM) {
#pragma unroll
        for (int k = 0; k < 8; ++k) a8 += gldf(&attn8[k * ADIM + tid]);
      }
      if (bid < 8 && tid < ADIM) gstf(&hproj8[bid * ADIM + tid], 0.f);
      sp = wred(sp);
      if (tid >= 512 && tid < 768 && lane == 0) smem[9760 + (wid - 8)] = sp;
      __syncthreads();
      float sden_t = smem[9760] + smem[9761] + smem[9762] + smem[9763];
      if (tid < ADIM) smem[HDIM + tid] = a8 / sden_t;
      if (tid >= 1020)
        out[VOFF + (size_t)t * SLEN + bid * 4 + (tid - 1020)] = smem[9764 + tid - 1020] / sden_t;
      __syncthreads();
      const float4* sm4 = (const float4*)smem;
      // x in regs: xr[0..15] = x[lane*16..+15]; xr[16..23] = x[1024+lane*8..+7]
      float xr[24];
#pragma unroll
      for (int k = 0; k < 4; ++k) {
        float4 f = sm4[lane * 4 + k];
        xr[k * 4 + 0] = f.x; xr[k * 4 + 1] = f.y; xr[k * 4 + 2] = f.z; xr[k * 4 + 3] = f.w;
      }
#pragma unroll
      for (int k = 0; k < 2; ++k) {
        float4 f = sm4[256 + lane * 2 + k];
        xr[16 + k * 4 + 0] = f.x; xr[16 + k * 4 + 1] = f.y;
        xr[16 + k * 4 + 2] = f.z; xr[16 + k * 4 + 3] = f.w;
      }
      int gw = bid * 16 + wid;
      float myscl = 0.f, myob = 0.f, myes = 0.f;
      if (lane < 13) {
        myscl = scl[gw * 13 + lane];
        int l0 = gw + lane * 4096;
        if (l0 < LANG) { myob = out_b[l0]; myes = escl[l0]; }
      }
      float* vout = out + (size_t)t * LANG;
      const bool fb = (t + 1 < NSTEP);
      float dsum = 0.f;
      float ae[8] = {0.f, 0.f, 0.f, 0.f, 0.f, 0.f, 0.f, 0.f};
      const char* wbase = wsb + OFF_W8 + (size_t)(gw * 13) * 1536;
      const uint4* r4b = (const uint4*)wbase;          // row r: [r*96 + lane]
      const uint2* r2b = (const uint2*)(wbase + 1024); // row r: [r*192 + lane]
      const uint2* e2b = (const uint2*)(wsb + OFF_EMBTB);
      uint4 q4[3]; uint2 q2[3]; uint2 e2[3];
#pragma unroll
      for (int i = 0; i < 3; ++i) {
        q4[i] = r4b[i * 96 + lane];
        q2[i] = r2b[i * 192 + lane];
        e2[i] = e2b[(size_t)(gw + i * 4096) * 64 + lane];
      }
#pragma unroll
      for (int r = 0; r < 13; ++r) {
        uint4 c4 = q4[r % 3];
        uint2 c2 = q2[r % 3];
        uint2 ce = e2[r % 3];
        if (r + 3 < 13) {
          q4[r % 3] = r4b[(r + 3) * 96 + lane];
          q2[r % 3] = r2b[(r + 3) * 192 + lane];
          e2[r % 3] = e2b[(size_t)(gw + (r + 3) * 4096) * 64 + lane];
        }
        float acc = 0.f;
        DOTW(c4.x, xr[0], xr[1], xr[2], xr[3]);
        DOTW(c4.y, xr[4], xr[5], xr[6], xr[7]);
        DOTW(c4.z, xr[8], xr[9], xr[10], xr[11]);
        DOTW(c4.w, xr[12], xr[13], xr[14], xr[15]);
        DOTW(c2.x, xr[16], xr[17], xr[18], xr[19]);
        DOTW(c2.y, xr[20], xr[21], xr[22], xr[23]);
        acc = wred(acc);
        float bc = __shfl(acc, 0);
        float sca = __shfl(myscl, r);
        float ob  = __shfl(myob, r);
        float es  = __shfl(myes, r);
        const bool valid = (r < 12) || (gw < LANG - 49152);
        float vv = (bc * sca + ob) * TEMPF;
        if (valid && lane == 0) vout[gw + r * 4096] = vv;
        if (fb) {
          float ev = valid ? expf(vv) : 0.f;
          dsum += ev;
          float w = ev * es;
          ae[0] += w * (float)((int)(ce.x << 24) >> 24);
          ae[1] += w * (float)((int)(ce.x << 16) >> 24);
          ae[2] += w * (float)((int)(ce.x << 8)  >> 24);
          ae[3] += w * (float)((int)ce.x >> 24);
          ae[4] += w * (float)((int)(ce.y << 24) >> 24);
          ae[5] += w * (float)((int)(ce.y << 16) >> 24);
          ae[6] += w * (float)((int)(ce.y << 8)  >> 24);
          ae[7] += w * (float)((int)ce.y >> 24);
        }
      }
      if (lane == 0) smem[640 + wid] = dsum;
      __syncthreads();
      if (fb) {
        if (tid == 0) {
          float tot = 0.f;
#pragma unroll
          for (int p = 0; p < 16; ++p) tot += smem[640 + p];
          gstf(&denwp[bid], tot);
        }
        float* big = smem + 1536;
#pragma unroll
        for (int i = 0; i < 8; ++i) big[wid * 512 + i * 64 + lane] = ae[i];
        __syncthreads();
#pragma unroll
        for (int st = 8; st; st >>= 1) {
          for (int i = tid; i < st * 512; i += NTHR) big[i] += big[i + st * 512];
          __syncthreads();
        }
        if (tid < 512) {
          int dim = ((tid & 63) << 3) | (tid >> 6);
          atomicAdd(&eanx8[(bid & 7) * EDIM + dim], big[tid]);
        }
      }
    }
    rnd++; gridbar(bar, bid, rnd);
  }
}

extern "C" void kernel_launch(void* const* d_in, const int* in_sizes, int n_in,
                              void* d_out, int out_size, void* d_ws, size_t ws_size,
                              hipStream_t stream) {
  const float* hidden  = (const float*)d_in[0];
  const float* emb_src = (const float*)d_in[1];
  const float* emb_T   = (const float*)d_in[2];
  const float* W_ih    = (const float*)d_in[3];
  const float* W_hh    = (const float*)d_in[4];
  const float* b_ih    = (const float*)d_in[5];
  const float* b_hh    = (const float*)d_in[6];
  const float* attn_W1 = (const float*)d_in[7];
  const float* attn_b1 = (const float*)d_in[8];
  const float* attn_v  = (const float*)d_in[9];
  const float* out_W   = (const float*)d_in[10];
  const float* out_b   = (const float*)d_in[11];
  float* out = (float*)d_out;
  char* wsb  = (char*)d_ws;

  hipMemsetAsync(wsb + OFF_BAR, 0, 4096, stream);

  void* args[] = {
    (void*)&hidden, (void*)&emb_src, (void*)&emb_T, (void*)&W_ih, (void*)&W_hh,
    (void*)&b_ih, (void*)&b_hh, (void*)&attn_W1, (void*)&attn_b1, (void*)&attn_v,
    (void*)&out_W, (void*)&out_b, (void*)&out, (void*)&wsb
  };
  hipLaunchCooperativeKernel((void*)k_decoder, dim3(NBLK), dim3(NTHR), args, 0, stream);
}

// Round 13
// 1923.198 us; speedup vs baseline: 1.0493x; 1.0493x over previous
//
#include <hip/hip_runtime.h>
#include <cstddef>
#include <cstdint>

#define LANG 50257
#define EDIM 512
#define HDIM 1024
#define ADIM 512
#define SLEN 1024
#define NSTEP 25
#define TEMPF 10.0f
#define SOSIDX 1
#define VOFF (NSTEP * LANG)
#define NBLK 256
#define NTHR 1024

// ---- ws byte offsets --------------------------------------------------------
#define OFF_W8     0u           // int8 out_W, permuted rows: 53248*1536
#define OFF_SCL    81788928u    // fp32 per-row scale, 53248
#define OFF_EMBTB  82001920u    // int8 emb_T rows: 50257*512 (region sized 51MB)
#define OFF_P      133465088u   // fp32 P[s][a] 1024*512
#define OFF_H      135562240u   // 2*1024
#define OFF_HPROJ8 135570432u   // 8*512
#define OFF_EANX8  135586816u   // 8*512
#define OFF_ATTN8  135603200u   // 8*512
#define OFF_DENWP  135619584u   // 256
#define OFF_SDENP  135620608u   // 256
#define OFF_ESCL   135627776u   // fp32 per-row emb scale, 50257 (ends 135828804)
#define OFF_BAR    135831552u   // padded flags: 4608 u32 = 18432 B (memset/launch)
// bar u32 layout: arrival blk i @ i*16 (i<256) | group-done g @ 4096+g*16 |
//                 group-go g @ 4352+g*16

__device__ __forceinline__ float wred(float x) {
#pragma unroll
  for (int off = 32; off; off >>= 1) x += __shfl_down(x, off);
  return x;
}

// device-scope (coherence-point) accesses, NO cache maintenance
__device__ __forceinline__ unsigned gldu(const unsigned* p) {
  return __hip_atomic_load((unsigned*)p, __ATOMIC_RELAXED, __HIP_MEMORY_SCOPE_AGENT);
}
__device__ __forceinline__ void gstu(unsigned* p, unsigned v) {
  __hip_atomic_store(p, v, __ATOMIC_RELAXED, __HIP_MEMORY_SCOPE_AGENT);
}
__device__ __forceinline__ float gldf(const float* p) {
  return __hip_atomic_load((float*)p, __ATOMIC_RELAXED, __HIP_MEMORY_SCOPE_AGENT);
}
__device__ __forceinline__ void gstf(float* p, float v) {
  __hip_atomic_store(p, v, __ATOMIC_RELAXED, __HIP_MEMORY_SCOPE_AGENT);
}

// Contention-free tree barrier: padded per-line flags, backoff polls,
// per-group go fan-out (16 pollers/line max). Relaxed device-scope only.
__device__ __forceinline__ void gridbar(unsigned* bar, int bid, unsigned round) {
  __syncthreads();
  const int tid = threadIdx.x;
  asm volatile("" ::: "memory");
  if (tid < 64) {
    if (tid == 0) {
      asm volatile("s_waitcnt vmcnt(0) lgkmcnt(0)" ::: "memory");
      gstu(&bar[bid * 16], round);
    }
    if ((bid & 15) == 0) {               // group leader: poll 16 padded lines
      unsigned v;
      for (;;) {
        v = (tid < 16) ? gldu(&bar[(bid + tid) * 16]) : round;
        if (!__any(v < round)) break;
        __builtin_amdgcn_s_sleep(1);
      }
      if (tid == 0) gstu(&bar[4096 + (bid >> 4) * 16], round);
    }
    if (bid == 0) {                      // root: poll 16 group-done lines
      unsigned v;
      for (;;) {
        v = (tid < 16) ? gldu(&bar[4096 + tid * 16]) : round;
        if (!__any(v < round)) break;
        __builtin_amdgcn_s_sleep(1);
      }
      if (tid < 16) gstu(&bar[4352 + tid * 16], round);   // fan-out 16 go flags
    }
    if (tid == 0) {                      // 16 blocks per go line
      while (gldu(&bar[4352 + (bid >> 4) * 16]) < round)
        __builtin_amdgcn_s_sleep(2);
    }
  }
  asm volatile("" ::: "memory");
  __syncthreads();
}

__device__ __forceinline__ void gridbar_f(unsigned* bar, int bid, unsigned round) {
  __syncthreads();
  if (threadIdx.x == 0) __threadfence();
  gridbar(bar, bid, round);
  if (threadIdx.x == 0) __threadfence();
  __syncthreads();
}

// int8 dot helpers: byte j of row = column j (identity layout)
#define DOTW(w, x0, x1, x2, x3)                                          \
  {                                                                      \
    acc += (float)((int)((w) << 24) >> 24) * (x0);                       \
    acc += (float)((int)((w) << 16) >> 24) * (x1);                       \
    acc += (float)((int)((w) << 8)  >> 24) * (x2);                       \
    acc += (float)((int)(w) >> 24)          * (x3);                      \
  }

__global__ __launch_bounds__(NTHR, 4) void k_decoder(
    const float* __restrict__ hidden, const float* __restrict__ emb_src,
    const float* __restrict__ emb_T,  const float* __restrict__ W_ih,
    const float* __restrict__ W_hh,   const float* __restrict__ b_ih,
    const float* __restrict__ b_hh,   const float* __restrict__ W1,
    const float* __restrict__ b1,     const float* __restrict__ vvec,
    const float* __restrict__ out_W,  const float* __restrict__ out_b,
    float* __restrict__ out, char* __restrict__ wsb) {
  __shared__ __align__(16) float smem[9776];
  const int tid = threadIdx.x, bid = blockIdx.x;
  const int wid = tid >> 6, lane = tid & 63;

  float* P      = (float*)(wsb + OFF_P);
  float* hws    = (float*)(wsb + OFF_H);
  float* hproj8 = (float*)(wsb + OFF_HPROJ8);
  float* eanx8  = (float*)(wsb + OFF_EANX8);
  float* attn8  = (float*)(wsb + OFF_ATTN8);
  float* denwp  = (float*)(wsb + OFF_DENWP);
  float* sdenp  = (float*)(wsb + OFF_SDENP);
  float* scl    = (float*)(wsb + OFF_SCL);
  float* escl   = (float*)(wsb + OFF_ESCL);
  unsigned* bar = (unsigned*)(wsb + OFF_BAR);
  unsigned rnd = 0;

  // ================= pre-phase ==============================================
  {
    uint2* w8w = (uint2*)(wsb + OFF_W8);
    const float4* src = (const float4*)out_W;
    int gw = bid * 16 + wid;
    for (int r = 0; r < 13; ++r) {
      int l = gw + r * 4096;
      if (r < 12 || l < LANG) {
        int p = gw * 13 + r;
        float4 f[6];
#pragma unroll
        for (int k = 0; k < 3; ++k) {
          f[2 * k]     = src[(size_t)l * 384 + k * 128 + lane * 2];
          f[2 * k + 1] = src[(size_t)l * 384 + k * 128 + lane * 2 + 1];
        }
        float mx = 0.f;
#pragma unroll
        for (int k = 0; k < 6; ++k)
          mx = fmaxf(mx, fmaxf(fmaxf(fabsf(f[k].x), fabsf(f[k].y)),
                               fmaxf(fabsf(f[k].z), fabsf(f[k].w))));
#pragma unroll
        for (int off = 32; off; off >>= 1) mx = fmaxf(mx, __shfl_down(mx, off));
        mx = __shfl(mx, 0);
        float inv = (mx > 0.f) ? 127.f / mx : 0.f;
#pragma unroll
        for (int k = 0; k < 3; ++k) {
          unsigned ux = 0, uy = 0;
          ux |= ((unsigned)((int)rintf(f[2*k].x * inv) & 255));
          ux |= ((unsigned)((int)rintf(f[2*k].y * inv) & 255)) << 8;
          ux |= ((unsigned)((int)rintf(f[2*k].z * inv) & 255)) << 16;
          ux |= ((unsigned)((int)rintf(f[2*k].w * inv) & 255)) << 24;
          uy |= ((unsigned)((int)rintf(f[2*k+1].x * inv) & 255));
          uy |= ((unsigned)((int)rintf(f[2*k+1].y * inv) & 255)) << 8;
          uy |= ((unsigned)((int)rintf(f[2*k+1].z * inv) & 255)) << 16;
          uy |= ((unsigned)((int)rintf(f[2*k+1].w * inv) & 255)) << 24;
          w8w[(size_t)p * 192 + k * 64 + lane] = make_uint2(ux, uy);
        }
        if (lane == 0) scl[p] = (mx > 0.f) ? mx / 127.f : 0.f;
      } else {
        int p = gw * 13 + r;
#pragma unroll
        for (int k = 0; k < 3; ++k)
          w8w[(size_t)p * 192 + k * 64 + lane] = make_uint2(0u, 0u);
        if (lane == 0) scl[p] = 0.f;
      }
    }
    // emb_T -> int8 per-row scale (row l: lane holds dims 8*lane..8*lane+7)
    {
      uint2* e8w = (uint2*)(wsb + OFF_EMBTB);
      for (int l = gw; l < LANG; l += 4096) {
        const float4* er = (const float4*)(emb_T + (size_t)l * 512);
        float4 f0 = er[lane * 2], f1 = er[lane * 2 + 1];
        float mx = fmaxf(fmaxf(fmaxf(fabsf(f0.x), fabsf(f0.y)),
                               fmaxf(fabsf(f0.z), fabsf(f0.w))),
                         fmaxf(fmaxf(fabsf(f1.x), fabsf(f1.y)),
                               fmaxf(fabsf(f1.z), fabsf(f1.w))));
#pragma unroll
        for (int off = 32; off; off >>= 1) mx = fmaxf(mx, __shfl_down(mx, off));
        mx = __shfl(mx, 0);
        float inv = (mx > 0.f) ? 127.f / mx : 0.f;
        unsigned ux = 0, uy = 0;
        ux |= ((unsigned)((int)rintf(f0.x * inv) & 255));
        ux |= ((unsigned)((int)rintf(f0.y * inv) & 255)) << 8;
        ux |= ((unsigned)((int)rintf(f0.z * inv) & 255)) << 16;
        ux |= ((unsigned)((int)rintf(f0.w * inv) & 255)) << 24;
        uy |= ((unsigned)((int)rintf(f1.x * inv) & 255));
        uy |= ((unsigned)((int)rintf(f1.y * inv) & 255)) << 8;
        uy |= ((unsigned)((int)rintf(f1.z * inv) & 255)) << 16;
        uy |= ((unsigned)((int)rintf(f1.w * inv) & 255)) << 24;
        e8w[(size_t)l * 64 + lane] = make_uint2(ux, uy);
        if (lane == 0) escl[l] = (mx > 0.f) ? mx / 127.f : 0.f;
      }
    }
    // P = emb_src @ W1[:A] + b1  (4 src rows per block)
    for (int i = tid; i < 4 * ADIM; i += NTHR)
      smem[i] = emb_src[(size_t)bid * 4 * ADIM + i];
    __syncthreads();
    if (tid < ADIM) {
      int a = tid;
      float bb = b1[a];
      float a0 = bb, a1 = bb, a2 = bb, a3 = bb;
      for (int k = 0; k < ADIM; ++k) {
        float w = W1[(size_t)k * ADIM + a];
        a0 += smem[k] * w; a1 += smem[512 + k] * w;
        a2 += smem[1024 + k] * w; a3 += smem[1536 + k] * w;
      }
      P[(size_t)(bid * 4 + 0) * ADIM + a] = a0;
      P[(size_t)(bid * 4 + 1) * ADIM + a] = a1;
      P[(size_t)(bid * 4 + 2) * ADIM + a] = a2;
      P[(size_t)(bid * 4 + 3) * ADIM + a] = a3;
    }
    if (bid == 0) {
      for (int i = tid; i < 8 * EDIM; i += NTHR)
        eanx8[i] = (i < EDIM) ? emb_T[(size_t)SOSIDX * EDIM + i] : 0.f;
      if (tid < 256) denwp[tid] = (tid == 0) ? 1.0f : 0.0f;
    }
    if (bid == 1) { for (int i = tid; i < 8 * ADIM; i += NTHR) hproj8[i] = 0.f; }
    if (bid == 2) { hws[tid] = hidden[tid]; }
    if (bid == 3) { for (int i = tid; i < 8 * ADIM; i += NTHR) attn8[i] = 0.f; }
  }
  rnd++; gridbar_f(bar, bid, rnd);

  for (int t = 0; t < NSTEP; ++t) {
    const int cur = t & 1, nxt = cur ^ 1;
    float* hold = hws + cur * HDIM;
    float* hnew = hws + nxt * HDIM;

    // ==== X: GRU + hproj scatter (+ zero attn8) =============================
    {
      float easum = 0.f;
      if (tid < EDIM) {
#pragma unroll
        for (int k = 0; k < 8; ++k) easum += gldf(&eanx8[k * EDIM + tid]);
      }
      float dp = 0.f;
      if (tid >= 512 && tid < 768) dp = gldf(&denwp[tid - 512]);
      smem[512 + tid] = gldf(&hold[tid]);
      if (bid < 8 && tid < ADIM) gstf(&attn8[bid * ADIM + tid], 0.f);
      dp = wred(dp);
      if (tid >= 512 && tid < 768 && lane == 0) smem[1632 + (wid - 8)] = dp;
      __syncthreads();
      float inv = 1.0f / (smem[1632] + smem[1633] + smem[1634] + smem[1635]);
      if (tid < EDIM) smem[tid] = easum * inv;
      __syncthreads();

      int jl = wid & 3, part = wid >> 2;
      int j = bid * 4 + jl;
      float ir = 0.f, iz = 0.f, in_ = 0.f;
#pragma unroll
      for (int k = 0; k < 2; ++k) {
        int e = part * 128 + k * 64 + lane;
        float x = smem[e];
        ir  += W_ih[(size_t)j * EDIM + e] * x;
        iz  += W_ih[(size_t)(j + HDIM) * EDIM + e] * x;
        in_ += W_ih[(size_t)(j + 2 * HDIM) * EDIM + e] * x;
      }
      float hr = 0.f, hz = 0.f, hn = 0.f;
#pragma unroll
      for (int k = 0; k < 4; ++k) {
        int e = part * 256 + k * 64 + lane;
        float x = smem[512 + e];
        hr += W_hh[(size_t)j * HDIM + e] * x;
        hz += W_hh[(size_t)(j + HDIM) * HDIM + e] * x;
        hn += W_hh[(size_t)(j + 2 * HDIM) * HDIM + e] * x;
      }
#pragma unroll
      for (int off = 32; off; off >>= 1) {
        ir += __shfl_down(ir, off);  iz += __shfl_down(iz, off);  in_ += __shfl_down(in_, off);
        hr += __shfl_down(hr, off);  hz += __shfl_down(hz, off);  hn += __shfl_down(hn, off);
      }
      if (lane == 0) {
        float* pb = smem + 1536 + (jl * 4 + part) * 6;
        pb[0] = ir; pb[1] = iz; pb[2] = in_; pb[3] = hr; pb[4] = hz; pb[5] = hn;
      }
      __syncthreads();
      if (tid < 4) {
        int jj = bid * 4 + tid;
        float sir = 0.f, siz = 0.f, sin_ = 0.f, shr = 0.f, shz = 0.f, shn = 0.f;
#pragma unroll
        for (int p = 0; p < 4; ++p) {
          float* pb = smem + 1536 + (tid * 4 + p) * 6;
          sir += pb[0]; siz += pb[1]; sin_ += pb[2];
          shr += pb[3]; shz += pb[4]; shn += pb[5];
        }
        float r = 1.f / (1.f + expf(-(sir + b_ih[jj] + shr + b_hh[jj])));
        float z = 1.f / (1.f + expf(-(siz + b_ih[jj + HDIM] + shz + b_hh[jj + HDIM])));
        float n = tanhf(sin_ + b_ih[jj + 2 * HDIM] + r * (shn + b_hh[jj + 2 * HDIM]));
        float hv = (1.f - z) * n + z * smem[512 + jj];
        gstf(&hnew[jj], hv);
        smem[1640 + tid] = hv;
      }
      __syncthreads();
      if (tid < ADIM) {
        float s = 0.f;
#pragma unroll
        for (int jl2 = 0; jl2 < 4; ++jl2)
          s += smem[1640 + jl2] * W1[(size_t)(ADIM + bid * 4 + jl2) * ADIM + tid];
        atomicAdd(&hproj8[(bid & 7) * ADIM + tid], s);
      }
    }
    rnd++; gridbar(bar, bid, rnd);

    // ==== Y: scores + sdenp + attn partials (+ zero eanx8) ==================
    {
      float hp = 0.f;
      if (tid < ADIM) {
#pragma unroll
        for (int k = 0; k < 8; ++k) hp += gldf(&hproj8[k * ADIM + tid]);
      }
      if (tid >= 512) smem[tid] = vvec[tid - 512];
      if (tid < ADIM) smem[tid] = hp;
      if (bid < 8 && tid < EDIM) gstf(&eanx8[bid * EDIM + tid], 0.f);
      __syncthreads();
      int sl = wid & 3, part = wid >> 2;
      int s = bid * 4 + sl;
      float acc = 0.f;
#pragma unroll
      for (int k = 0; k < 2; ++k) {
        int a = part * 128 + k * 64 + lane;
        acc += smem[512 + a] * tanhf(P[(size_t)s * ADIM + a] + smem[a]);
      }
      acc = wred(acc);
      if (lane == 0) smem[1024 + wid] = acc;
      __syncthreads();
      if (tid < 4) {
        float tot = smem[1024 + tid] + smem[1028 + tid] + smem[1032 + tid] + smem[1036 + tid];
        float e = expf(tot);
        smem[1040 + tid] = e;
        smem[9764 + tid] = e;     // persists across barrier for Z's w_out
      }
      __syncthreads();
      if (tid == 0)
        gstf(&sdenp[bid], smem[1040] + smem[1041] + smem[1042] + smem[1043]);
      if (tid < ADIM) {
        float pa = smem[1040] * emb_src[(size_t)(bid * 4 + 0) * ADIM + tid]
                 + smem[1041] * emb_src[(size_t)(bid * 4 + 1) * ADIM + tid]
                 + smem[1042] * emb_src[(size_t)(bid * 4 + 2) * ADIM + tid]
                 + smem[1043] * emb_src[(size_t)(bid * 4 + 3) * ADIM + tid];
        atomicAdd(&attn8[(bid & 7) * ADIM + tid], pa);
      }
    }
    rnd++; gridbar(bar, bid, rnd);

    // ==== Z: fused logits + feedback single-stream pipeline =================
    {
      float sp = 0.f;
      if (tid >= 512 && tid < 768) sp = gldf(&sdenp[tid - 512]);
      smem[tid] = gldf(&hnew[tid]);
      float a8 = 0.f;
      if (tid < ADIM) {
#pragma unroll
        for (int k = 0; k < 8; ++k) a8 += gldf(&attn8[k * ADIM + tid]);
      }
      if (bid < 8 && tid < ADIM) gstf(&hproj8[bid * ADIM + tid], 0.f);
      sp = wred(sp);
      if (tid >= 512 && tid < 768 && lane == 0) smem[9760 + (wid - 8)] = sp;
      __syncthreads();
      float sden_t = smem[9760] + smem[9761] + smem[9762] + smem[9763];
      if (tid < ADIM) smem[HDIM + tid] = a8 / sden_t;
      if (tid >= 1020)
        out[VOFF + (size_t)t * SLEN + bid * 4 + (tid - 1020)] = smem[9764 + tid - 1020] / sden_t;
      __syncthreads();
      const float4* sm4 = (const float4*)smem;
      // x in regs: xr[0..15] = x[lane*16..+15]; xr[16..23] = x[1024+lane*8..+7]
      float xr[24];
#pragma unroll
      for (int k = 0; k < 4; ++k) {
        float4 f = sm4[lane * 4 + k];
        xr[k * 4 + 0] = f.x; xr[k * 4 + 1] = f.y; xr[k * 4 + 2] = f.z; xr[k * 4 + 3] = f.w;
      }
#pragma unroll
      for (int k = 0; k < 2; ++k) {
        float4 f = sm4[256 + lane * 2 + k];
        xr[16 + k * 4 + 0] = f.x; xr[16 + k * 4 + 1] = f.y;
        xr[16 + k * 4 + 2] = f.z; xr[16 + k * 4 + 3] = f.w;
      }
      int gw = bid * 16 + wid;
      float myscl = 0.f, myob = 0.f, myes = 0.f;
      if (lane < 13) {
        myscl = scl[gw * 13 + lane];
        int l0 = gw + lane * 4096;
        if (l0 < LANG) { myob = out_b[l0]; myes = escl[l0]; }
      }
      float* vout = out + (size_t)t * LANG;
      const bool fb = (t + 1 < NSTEP);
      float dsum = 0.f;
      float ae[8] = {0.f, 0.f, 0.f, 0.f, 0.f, 0.f, 0.f, 0.f};
      const char* wbase = wsb + OFF_W8 + (size_t)(gw * 13) * 1536;
      const uint4* r4b = (const uint4*)wbase;          // row r: [r*96 + lane]
      const uint2* r2b = (const uint2*)(wbase + 1024); // row r: [r*192 + lane]
      const uint2* e2b = (const uint2*)(wsb + OFF_EMBTB);
      uint4 q4[3]; uint2 q2[3]; uint2 e2[3];
#pragma unroll
      for (int i = 0; i < 3; ++i) {
        q4[i] = r4b[i * 96 + lane];
        q2[i] = r2b[i * 192 + lane];
        e2[i] = e2b[(size_t)(gw + i * 4096) * 64 + lane];
      }
#pragma unroll
      for (int r = 0; r < 13; ++r) {
        uint4 c4 = q4[r % 3];
        uint2 c2 = q2[r % 3];
        uint2 ce = e2[r % 3];
        if (r + 3 < 13) {
          q4[r % 3] = r4b[(r + 3) * 96 + lane];
          q2[r % 3] = r2b[(r + 3) * 192 + lane];
          e2[r % 3] = e2b[(size_t)(gw + (r + 3) * 4096) * 64 + lane];
        }
        float acc = 0.f;
        DOTW(c4.x, xr[0], xr[1], xr[2], xr[3]);
        DOTW(c4.y, xr[4], xr[5], xr[6], xr[7]);
        DOTW(c4.z, xr[8], xr[9], xr[10], xr[11]);
        DOTW(c4.w, xr[12], xr[13], xr[14], xr[15]);
        DOTW(c2.x, xr[16], xr[17], xr[18], xr[19]);
        DOTW(c2.y, xr[20], xr[21], xr[22], xr[23]);
        acc = wred(acc);
        float bc = __shfl(acc, 0);
        float sca = __shfl(myscl, r);
        float ob  = __shfl(myob, r);
        float es  = __shfl(myes, r);
        const bool valid = (r < 12) || (gw < LANG - 49152);
        float vv = (bc * sca + ob) * TEMPF;
        if (valid && lane == 0) vout[gw + r * 4096] = vv;
        if (fb) {
          float ev = valid ? expf(vv) : 0.f;
          dsum += ev;
          float w = ev * es;
          ae[0] += w * (float)((int)(ce.x << 24) >> 24);
          ae[1] += w * (float)((int)(ce.x << 16) >> 24);
          ae[2] += w * (float)((int)(ce.x << 8)  >> 24);
          ae[3] += w * (float)((int)ce.x >> 24);
          ae[4] += w * (float)((int)(ce.y << 24) >> 24);
          ae[5] += w * (float)((int)(ce.y << 16) >> 24);
          ae[6] += w * (float)((int)(ce.y << 8)  >> 24);
          ae[7] += w * (float)((int)ce.y >> 24);
        }
      }
      if (lane == 0) smem[640 + wid] = dsum;
      __syncthreads();
      if (fb) {
        if (tid == 0) {
          float tot = 0.f;
#pragma unroll
          for (int p = 0; p < 16; ++p) tot += smem[640 + p];
          gstf(&denwp[bid], tot);
        }
        float* big = smem + 1536;
#pragma unroll
        for (int i = 0; i < 8; ++i) big[wid * 512 + i * 64 + lane] = ae[i];
        __syncthreads();
#pragma unroll
        for (int st = 8; st; st >>= 1) {
          for (int i = tid; i < st * 512; i += NTHR) big[i] += big[i + st * 512];
          __syncthreads();
        }
        if (tid < 512) {
          int dim = ((tid & 63) << 3) | (tid >> 6);
          atomicAdd(&eanx8[(bid & 7) * EDIM + dim], big[tid]);
        }
      }
    }
    rnd++; gridbar(bar, bid, rnd);
  }
}

extern "C" void kernel_launch(void* const* d_in, const int* in_sizes, int n_in,
                              void* d_out, int out_size, void* d_ws, size_t ws_size,
                              hipStream_t stream) {
  const float* hidden  = (const float*)d_in[0];
  const float* emb_src = (const float*)d_in[1];
  const float* emb_T   = (const float*)d_in[2];
  const float* W_ih    = (const float*)d_in[3];
  const float* W_hh    = (const float*)d_in[4];
  const float* b_ih    = (const float*)d_in[5];
  const float* b_hh    = (const float*)d_in[6];
  const float* attn_W1 = (const float*)d_in[7];
  const float* attn_b1 = (const float*)d_in[8];
  const float* attn_v  = (const float*)d_in[9];
  const float* out_W   = (const float*)d_in[10];
  const float* out_b   = (const float*)d_in[11];
  float* out = (float*)d_out;
  char* wsb  = (char*)d_ws;

  hipMemsetAsync(wsb + OFF_BAR, 0, 18432, stream);

  void* args[] = {
    (void*)&hidden, (void*)&emb_src, (void*)&emb_T, (void*)&W_ih, (void*)&W_hh,
    (void*)&b_ih, (void*)&b_hh, (void*)&attn_W1, (void*)&attn_b1, (void*)&attn_v,
    (void*)&out_W, (void*)&out_b, (void*)&out, (void*)&wsb
  };
  hipLaunchCooperativeKernel((void*)k_decoder, dim3(NBLK), dim3(NTHR), args, 0, stream);
}

// Round 14
// 1743.991 us; speedup vs baseline: 1.1571x; 1.1028x over previous
//
#include <hip/hip_runtime.h>
#include <cstddef>
#include <cstdint>

#define LANG 50257
#define EDIM 512
#define HDIM 1024
#define ADIM 512
#define SLEN 1024
#define NSTEP 25
#define TEMPF 10.0f
#define SOSIDX 1
#define VOFF (NSTEP * LANG)
#define NBLK 256
#define NTHR 1024

// ---- ws byte offsets --------------------------------------------------------
#define OFF_W8     0u           // int8 out_W, permuted rows: 53248*1536
#define OFF_SCL    81788928u    // fp32 per-row scale, 53248
#define OFF_EMBTB  82001920u    // int8 emb_T rows: 50257*512
#define OFF_H      135562240u   // 2*1024
#define OFF_HPROJ8 135570432u   // 8*512
#define OFF_EANX8  135586816u   // 8*512
#define OFF_ATTN8  135603200u   // 8*512
#define OFF_DENWP  135619584u   // 256
#define OFF_SDENP  135620608u   // 256
#define OFF_ESCL   135627776u   // fp32 per-row emb scale, 50257
#define OFF_BAR    135831552u   // padded flags: 4608 u32 (memset per launch)

__device__ __forceinline__ float wred(float x) {
#pragma unroll
  for (int off = 32; off; off >>= 1) x += __shfl_down(x, off);
  return x;
}

// device-scope (coherence-point) accesses, NO cache maintenance
__device__ __forceinline__ unsigned gldu(const unsigned* p) {
  return __hip_atomic_load((unsigned*)p, __ATOMIC_RELAXED, __HIP_MEMORY_SCOPE_AGENT);
}
__device__ __forceinline__ void gstu(unsigned* p, unsigned v) {
  __hip_atomic_store(p, v, __ATOMIC_RELAXED, __HIP_MEMORY_SCOPE_AGENT);
}
__device__ __forceinline__ float gldf(const float* p) {
  return __hip_atomic_load((float*)p, __ATOMIC_RELAXED, __HIP_MEMORY_SCOPE_AGENT);
}
__device__ __forceinline__ void gstf(float* p, float v) {
  __hip_atomic_store(p, v, __ATOMIC_RELAXED, __HIP_MEMORY_SCOPE_AGENT);
}

// Contention-free tree barrier (R13, proven): padded flags, backoff, go fan-out.
__device__ __forceinline__ void gridbar(unsigned* bar, int bid, unsigned round) {
  __syncthreads();
  const int tid = threadIdx.x;
  asm volatile("" ::: "memory");
  if (tid < 64) {
    if (tid == 0) {
      asm volatile("s_waitcnt vmcnt(0) lgkmcnt(0)" ::: "memory");
      gstu(&bar[bid * 16], round);
    }
    if ((bid & 15) == 0) {
      unsigned v;
      for (;;) {
        v = (tid < 16) ? gldu(&bar[(bid + tid) * 16]) : round;
        if (!__any(v < round)) break;
        __builtin_amdgcn_s_sleep(1);
      }
      if (tid == 0) gstu(&bar[4096 + (bid >> 4) * 16], round);
    }
    if (bid == 0) {
      unsigned v;
      for (;;) {
        v = (tid < 16) ? gldu(&bar[4096 + tid * 16]) : round;
        if (!__any(v < round)) break;
        __builtin_amdgcn_s_sleep(1);
      }
      if (tid < 16) gstu(&bar[4352 + tid * 16], round);
    }
    if (tid == 0) {
      while (gldu(&bar[4352 + (bid >> 4) * 16]) < round)
        __builtin_amdgcn_s_sleep(2);
    }
  }
  asm volatile("" ::: "memory");
  __syncthreads();
}

__device__ __forceinline__ void gridbar_f(unsigned* bar, int bid, unsigned round) {
  __syncthreads();
  if (threadIdx.x == 0) __threadfence();
  gridbar(bar, bid, round);
  if (threadIdx.x == 0) __threadfence();
  __syncthreads();
}

// int8 dot helpers: byte j of row = column j (identity layout)
#define DOTW(w, x0, x1, x2, x3)                                          \
  {                                                                      \
    acc += (float)((int)((w) << 24) >> 24) * (x0);                       \
    acc += (float)((int)((w) << 16) >> 24) * (x1);                       \
    acc += (float)((int)((w) << 8)  >> 24) * (x2);                       \
    acc += (float)((int)(w) >> 24)          * (x3);                      \
  }

__global__ __launch_bounds__(NTHR, 4) void k_decoder(
    const float* __restrict__ hidden, const float* __restrict__ emb_src,
    const float* __restrict__ emb_T,  const float* __restrict__ W_ih,
    const float* __restrict__ W_hh,   const float* __restrict__ b_ih,
    const float* __restrict__ b_hh,   const float* __restrict__ W1,
    const float* __restrict__ b1,     const float* __restrict__ vvec,
    const float* __restrict__ out_W,  const float* __restrict__ out_b,
    float* __restrict__ out, char* __restrict__ wsb) {
  __shared__ __align__(16) float smem[9776];       // work area (R13 layout)
  __shared__ __align__(16) float sWih[6144];       // [4 j][3 g][512]  24 KB
  __shared__ __align__(16) float sWhh[12288];      // [4 j][3 g][1024] 48 KB
  __shared__ __align__(16) float sW1h[2048];       // [4 j][512]        8 KB
  __shared__ __align__(16) float sP[2048];         // [4 s][512]        8 KB
  __shared__ __align__(16) float sE[2048];         // [4 s][512]        8 KB
  const int tid = threadIdx.x, bid = blockIdx.x;
  const int wid = tid >> 6, lane = tid & 63;

  float* hws    = (float*)(wsb + OFF_H);
  float* hproj8 = (float*)(wsb + OFF_HPROJ8);
  float* eanx8  = (float*)(wsb + OFF_EANX8);
  float* attn8  = (float*)(wsb + OFF_ATTN8);
  float* denwp  = (float*)(wsb + OFF_DENWP);
  float* sdenp  = (float*)(wsb + OFF_SDENP);
  float* scl    = (float*)(wsb + OFF_SCL);
  float* escl   = (float*)(wsb + OFF_ESCL);
  unsigned* bar = (unsigned*)(wsb + OFF_BAR);
  unsigned rnd = 0;

  // ================= pre-phase ==============================================
  {
    uint2* w8w = (uint2*)(wsb + OFF_W8);
    const float4* src = (const float4*)out_W;
    int gw = bid * 16 + wid;
    for (int r = 0; r < 13; ++r) {
      int l = gw + r * 4096;
      if (r < 12 || l < LANG) {
        int p = gw * 13 + r;
        float4 f[6];
#pragma unroll
        for (int k = 0; k < 3; ++k) {
          f[2 * k]     = src[(size_t)l * 384 + k * 128 + lane * 2];
          f[2 * k + 1] = src[(size_t)l * 384 + k * 128 + lane * 2 + 1];
        }
        float mx = 0.f;
#pragma unroll
        for (int k = 0; k < 6; ++k)
          mx = fmaxf(mx, fmaxf(fmaxf(fabsf(f[k].x), fabsf(f[k].y)),
                               fmaxf(fabsf(f[k].z), fabsf(f[k].w))));
#pragma unroll
        for (int off = 32; off; off >>= 1) mx = fmaxf(mx, __shfl_down(mx, off));
        mx = __shfl(mx, 0);
        float inv = (mx > 0.f) ? 127.f / mx : 0.f;
#pragma unroll
        for (int k = 0; k < 3; ++k) {
          unsigned ux = 0, uy = 0;
          ux |= ((unsigned)((int)rintf(f[2*k].x * inv) & 255));
          ux |= ((unsigned)((int)rintf(f[2*k].y * inv) & 255)) << 8;
          ux |= ((unsigned)((int)rintf(f[2*k].z * inv) & 255)) << 16;
          ux |= ((unsigned)((int)rintf(f[2*k].w * inv) & 255)) << 24;
          uy |= ((unsigned)((int)rintf(f[2*k+1].x * inv) & 255));
          uy |= ((unsigned)((int)rintf(f[2*k+1].y * inv) & 255)) << 8;
          uy |= ((unsigned)((int)rintf(f[2*k+1].z * inv) & 255)) << 16;
          uy |= ((unsigned)((int)rintf(f[2*k+1].w * inv) & 255)) << 24;
          w8w[(size_t)p * 192 + k * 64 + lane] = make_uint2(ux, uy);
        }
        if (lane == 0) scl[p] = (mx > 0.f) ? mx / 127.f : 0.f;
      } else {
        int p = gw * 13 + r;
#pragma unroll
        for (int k = 0; k < 3; ++k)
          w8w[(size_t)p * 192 + k * 64 + lane] = make_uint2(0u, 0u);
        if (lane == 0) scl[p] = 0.f;
      }
    }
    // emb_T -> int8 per-row scale
    {
      uint2* e8w = (uint2*)(wsb + OFF_EMBTB);
      for (int l = gw; l < LANG; l += 4096) {
        const float4* er = (const float4*)(emb_T + (size_t)l * 512);
        float4 f0 = er[lane * 2], f1 = er[lane * 2 + 1];
        float mx = fmaxf(fmaxf(fmaxf(fabsf(f0.x), fabsf(f0.y)),
                               fmaxf(fabsf(f0.z), fabsf(f0.w))),
                         fmaxf(fmaxf(fabsf(f1.x), fabsf(f1.y)),
                               fmaxf(fabsf(f1.z), fabsf(f1.w))));
#pragma unroll
        for (int off = 32; off; off >>= 1) mx = fmaxf(mx, __shfl_down(mx, off));
        mx = __shfl(mx, 0);
        float inv = (mx > 0.f) ? 127.f / mx : 0.f;
        unsigned ux = 0, uy = 0;
        ux |= ((unsigned)((int)rintf(f0.x * inv) & 255));
        ux |= ((unsigned)((int)rintf(f0.y * inv) & 255)) << 8;
        ux |= ((unsigned)((int)rintf(f0.z * inv) & 255)) << 16;
        ux |= ((unsigned)((int)rintf(f0.w * inv) & 255)) << 24;
        uy |= ((unsigned)((int)rintf(f1.x * inv) & 255));
        uy |= ((unsigned)((int)rintf(f1.y * inv) & 255)) << 8;
        uy |= ((unsigned)((int)rintf(f1.z * inv) & 255)) << 16;
        uy |= ((unsigned)((int)rintf(f1.w * inv) & 255)) << 24;
        e8w[(size_t)l * 64 + lane] = make_uint2(ux, uy);
        if (lane == 0) escl[l] = (mx > 0.f) ? mx / 127.f : 0.f;
      }
    }
    // persistent LDS fills (step-invariant, block-private)
    for (int i = tid; i < 2048; i += NTHR)
      sE[i] = emb_src[(size_t)bid * 2048 + i];
    for (int i = tid; i < 6144; i += NTHR) {
      int jl = i / 1536, rem = i % 1536, g = rem >> 9, e = rem & 511;
      sWih[i] = W_ih[(size_t)(bid * 4 + jl + g * HDIM) * EDIM + e];
    }
    for (int i = tid; i < 12288; i += NTHR) {
      int jl = i / 3072, rem = i % 3072, g = rem >> 10, e = rem & 1023;
      sWhh[i] = W_hh[(size_t)(bid * 4 + jl + g * HDIM) * HDIM + e];
    }
    for (int i = tid; i < 2048; i += NTHR) {
      int jl = i >> 9, a = i & 511;
      sW1h[i] = W1[(size_t)(ADIM + bid * 4 + jl) * ADIM + a];
    }
    __syncthreads();
    // P (block-private) -> sP
    if (tid < ADIM) {
      float bb = b1[tid];
      float a0 = bb, a1 = bb, a2 = bb, a3 = bb;
      for (int k = 0; k < ADIM; ++k) {
        float w = W1[(size_t)k * ADIM + tid];
        a0 += sE[k] * w; a1 += sE[512 + k] * w;
        a2 += sE[1024 + k] * w; a3 += sE[1536 + k] * w;
      }
      sP[tid] = a0; sP[512 + tid] = a1; sP[1024 + tid] = a2; sP[1536 + tid] = a3;
    }
    if (bid == 0) {
      for (int i = tid; i < 8 * EDIM; i += NTHR)
        eanx8[i] = (i < EDIM) ? emb_T[(size_t)SOSIDX * EDIM + i] : 0.f;
      if (tid < 256) denwp[tid] = (tid == 0) ? 1.0f : 0.0f;
    }
    if (bid == 1) { for (int i = tid; i < 8 * ADIM; i += NTHR) hproj8[i] = 0.f; }
    if (bid == 2) { hws[tid] = hidden[tid]; }
    if (bid == 3) { for (int i = tid; i < 8 * ADIM; i += NTHR) attn8[i] = 0.f; }
  }
  rnd++; gridbar_f(bar, bid, rnd);

  for (int t = 0; t < NSTEP; ++t) {
    const int cur = t & 1, nxt = cur ^ 1;
    float* hold = hws + cur * HDIM;
    float* hnew = hws + nxt * HDIM;

    // ==== X: GRU (LDS weights) + hproj scatter (+ zero attn8) ===============
    {
      float easum = 0.f;
      if (tid < EDIM) {
#pragma unroll
        for (int k = 0; k < 8; ++k) easum += gldf(&eanx8[k * EDIM + tid]);
      }
      float dp = 0.f;
      if (tid >= 512 && tid < 768) dp = gldf(&denwp[tid - 512]);
      smem[512 + tid] = gldf(&hold[tid]);
      if (bid < 8 && tid < ADIM) gstf(&attn8[bid * ADIM + tid], 0.f);
      dp = wred(dp);
      if (tid >= 512 && tid < 768 && lane == 0) smem[1632 + (wid - 8)] = dp;
      __syncthreads();
      float inv = 1.0f / (smem[1632] + smem[1633] + smem[1634] + smem[1635]);
      if (tid < EDIM) smem[tid] = easum * inv;
      __syncthreads();

      int jl = wid & 3, part = wid >> 2;
      float ir = 0.f, iz = 0.f, in_ = 0.f;
#pragma unroll
      for (int k = 0; k < 2; ++k) {
        int e = part * 128 + k * 64 + lane;
        float x = smem[e];
        ir  += sWih[jl * 1536 + e] * x;
        iz  += sWih[jl * 1536 + 512 + e] * x;
        in_ += sWih[jl * 1536 + 1024 + e] * x;
      }
      float hr = 0.f, hz = 0.f, hn = 0.f;
#pragma unroll
      for (int k = 0; k < 4; ++k) {
        int e = part * 256 + k * 64 + lane;
        float x = smem[512 + e];
        hr += sWhh[jl * 3072 + e] * x;
        hz += sWhh[jl * 3072 + 1024 + e] * x;
        hn += sWhh[jl * 3072 + 2048 + e] * x;
      }
#pragma unroll
      for (int off = 32; off; off >>= 1) {
        ir += __shfl_down(ir, off);  iz += __shfl_down(iz, off);  in_ += __shfl_down(in_, off);
        hr += __shfl_down(hr, off);  hz += __shfl_down(hz, off);  hn += __shfl_down(hn, off);
      }
      if (lane == 0) {
        float* pb = smem + 1536 + (jl * 4 + part) * 6;
        pb[0] = ir; pb[1] = iz; pb[2] = in_; pb[3] = hr; pb[4] = hz; pb[5] = hn;
      }
      __syncthreads();
      if (tid < 4) {
        int jj = bid * 4 + tid;
        float sir = 0.f, siz = 0.f, sin_ = 0.f, shr = 0.f, shz = 0.f, shn = 0.f;
#pragma unroll
        for (int p = 0; p < 4; ++p) {
          float* pb = smem + 1536 + (tid * 4 + p) * 6;
          sir += pb[0]; siz += pb[1]; sin_ += pb[2];
          shr += pb[3]; shz += pb[4]; shn += pb[5];
        }
        float r = 1.f / (1.f + expf(-(sir + b_ih[jj] + shr + b_hh[jj])));
        float z = 1.f / (1.f + expf(-(siz + b_ih[jj + HDIM] + shz + b_hh[jj + HDIM])));
        float n = tanhf(sin_ + b_ih[jj + 2 * HDIM] + r * (shn + b_hh[jj + 2 * HDIM]));
        float hv = (1.f - z) * n + z * smem[512 + jj];
        gstf(&hnew[jj], hv);
        smem[1640 + tid] = hv;
      }
      __syncthreads();
      if (tid < ADIM) {
        float s = 0.f;
#pragma unroll
        for (int jl2 = 0; jl2 < 4; ++jl2)
          s += smem[1640 + jl2] * sW1h[jl2 * 512 + tid];
        atomicAdd(&hproj8[(bid & 7) * ADIM + tid], s);
      }
    }
    rnd++; gridbar(bar, bid, rnd);

    // ==== Y: scores (LDS P) + sdenp + attn partials (+ zero eanx8) ==========
    {
      float hp = 0.f;
      if (tid < ADIM) {
#pragma unroll
        for (int k = 0; k < 8; ++k) hp += gldf(&hproj8[k * ADIM + tid]);
      }
      if (tid >= 512) smem[tid] = vvec[tid - 512];
      if (tid < ADIM) smem[tid] = hp;
      if (bid < 8 && tid < EDIM) gstf(&eanx8[bid * EDIM + tid], 0.f);
      __syncthreads();
      int sl = wid & 3, part = wid >> 2;
      float acc = 0.f;
#pragma unroll
      for (int k = 0; k < 2; ++k) {
        int a = part * 128 + k * 64 + lane;
        acc += smem[512 + a] * tanhf(sP[sl * 512 + a] + smem[a]);
      }
      acc = wred(acc);
      if (lane == 0) smem[1024 + wid] = acc;
      __syncthreads();
      if (tid < 4) {
        float tot = smem[1024 + tid] + smem[1028 + tid] + smem[1032 + tid] + smem[1036 + tid];
        float e = expf(tot);
        smem[1040 + tid] = e;
        smem[9764 + tid] = e;     // persists across barrier for Z's w_out
      }
      __syncthreads();
      if (tid == 0)
        gstf(&sdenp[bid], smem[1040] + smem[1041] + smem[1042] + smem[1043]);
      if (tid < ADIM) {
        float pa = smem[1040] * sE[tid] + smem[1041] * sE[512 + tid]
                 + smem[1042] * sE[1024 + tid] + smem[1043] * sE[1536 + tid];
        atomicAdd(&attn8[(bid & 7) * ADIM + tid], pa);
      }
    }
    rnd++; gridbar(bar, bid, rnd);

    // ==== Z: fused logits + feedback single-stream pipeline (R13) ===========
    {
      float sp = 0.f;
      if (tid >= 512 && tid < 768) sp = gldf(&sdenp[tid - 512]);
      smem[tid] = gldf(&hnew[tid]);
      float a8 = 0.f;
      if (tid < ADIM) {
#pragma unroll
        for (int k = 0; k < 8; ++k) a8 += gldf(&attn8[k * ADIM + tid]);
      }
      if (bid < 8 && tid < ADIM) gstf(&hproj8[bid * ADIM + tid], 0.f);
      sp = wred(sp);
      if (tid >= 512 && tid < 768 && lane == 0) smem[9760 + (wid - 8)] = sp;
      __syncthreads();
      float sden_t = smem[9760] + smem[9761] + smem[9762] + smem[9763];
      if (tid < ADIM) smem[HDIM + tid] = a8 / sden_t;
      if (tid >= 1020)
        out[VOFF + (size_t)t * SLEN + bid * 4 + (tid - 1020)] = smem[9764 + tid - 1020] / sden_t;
      __syncthreads();
      const float4* sm4 = (const float4*)smem;
      float xr[24];
#pragma unroll
      for (int k = 0; k < 4; ++k) {
        float4 f = sm4[lane * 4 + k];
        xr[k * 4 + 0] = f.x; xr[k * 4 + 1] = f.y; xr[k * 4 + 2] = f.z; xr[k * 4 + 3] = f.w;
      }
#pragma unroll
      for (int k = 0; k < 2; ++k) {
        float4 f = sm4[256 + lane * 2 + k];
        xr[16 + k * 4 + 0] = f.x; xr[16 + k * 4 + 1] = f.y;
        xr[16 + k * 4 + 2] = f.z; xr[16 + k * 4 + 3] = f.w;
      }
      int gw = bid * 16 + wid;
      float myscl = 0.f, myob = 0.f, myes = 0.f;
      if (lane < 13) {
        myscl = scl[gw * 13 + lane];
        int l0 = gw + lane * 4096;
        if (l0 < LANG) { myob = out_b[l0]; myes = escl[l0]; }
      }
      float* vout = out + (size_t)t * LANG;
      const bool fb = (t + 1 < NSTEP);
      float dsum = 0.f;
      float ae[8] = {0.f, 0.f, 0.f, 0.f, 0.f, 0.f, 0.f, 0.f};
      const char* wbase = wsb + OFF_W8 + (size_t)(gw * 13) * 1536;
      const uint4* r4b = (const uint4*)wbase;
      const uint2* r2b = (const uint2*)(wbase + 1024);
      const uint2* e2b = (const uint2*)(wsb + OFF_EMBTB);
      uint4 q4[3]; uint2 q2[3]; uint2 e2[3];
#pragma unroll
      for (int i = 0; i < 3; ++i) {
        q4[i] = r4b[i * 96 + lane];
        q2[i] = r2b[i * 192 + lane];
        e2[i] = e2b[(size_t)(gw + i * 4096) * 64 + lane];
      }
#pragma unroll
      for (int r = 0; r < 13; ++r) {
        uint4 c4 = q4[r % 3];
        uint2 c2 = q2[r % 3];
        uint2 ce = e2[r % 3];
        if (r + 3 < 13) {
          q4[r % 3] = r4b[(r + 3) * 96 + lane];
          q2[r % 3] = r2b[(r + 3) * 192 + lane];
          e2[r % 3] = e2b[(size_t)(gw + (r + 3) * 4096) * 64 + lane];
        }
        float acc = 0.f;
        DOTW(c4.x, xr[0], xr[1], xr[2], xr[3]);
        DOTW(c4.y, xr[4], xr[5], xr[6], xr[7]);
        DOTW(c4.z, xr[8], xr[9], xr[10], xr[11]);
        DOTW(c4.w, xr[12], xr[13], xr[14], xr[15]);
        DOTW(c2.x, xr[16], xr[17], xr[18], xr[19]);
        DOTW(c2.y, xr[20], xr[21], xr[22], xr[23]);
        acc = wred(acc);
        float bc = __shfl(acc, 0);
        float sca = __shfl(myscl, r);
        float ob  = __shfl(myob, r);
        float es  = __shfl(myes, r);
        const bool valid = (r < 12) || (gw < LANG - 49152);
        float vv = (bc * sca + ob) * TEMPF;
        if (valid && lane == 0) vout[gw + r * 4096] = vv;
        if (fb) {
          float ev = valid ? expf(vv) : 0.f;
          dsum += ev;
          float w = ev * es;
          ae[0] += w * (float)((int)(ce.x << 24) >> 24);
          ae[1] += w * (float)((int)(ce.x << 16) >> 24);
          ae[2] += w * (float)((int)(ce.x << 8)  >> 24);
          ae[3] += w * (float)((int)ce.x >> 24);
          ae[4] += w * (float)((int)(ce.y << 24) >> 24);
          ae[5] += w * (float)((int)(ce.y << 16) >> 24);
          ae[6] += w * (float)((int)(ce.y << 8)  >> 24);
          ae[7] += w * (float)((int)ce.y >> 24);
        }
      }
      if (lane == 0) smem[640 + wid] = dsum;
      __syncthreads();
      if (fb) {
        if (tid == 0) {
          float tot = 0.f;
#pragma unroll
          for (int p = 0; p < 16; ++p) tot += smem[640 + p];
          gstf(&denwp[bid], tot);
        }
        float* big = smem + 1536;
#pragma unroll
        for (int i = 0; i < 8; ++i) big[wid * 512 + i * 64 + lane] = ae[i];
        __syncthreads();
#pragma unroll
        for (int st = 8; st; st >>= 1) {
          for (int i = tid; i < st * 512; i += NTHR) big[i] += big[i + st * 512];
          __syncthreads();
        }
        if (tid < 512) {
          int dim = ((tid & 63) << 3) | (tid >> 6);
          atomicAdd(&eanx8[(bid & 7) * EDIM + dim], big[tid]);
        }
      }
    }
    rnd++; gridbar(bar, bid, rnd);
  }
}

extern "C" void kernel_launch(void* const* d_in, const int* in_sizes, int n_in,
                              void* d_out, int out_size, void* d_ws, size_t ws_size,
                              hipStream_t stream) {
  const float* hidden  = (const float*)d_in[0];
  const float* emb_src = (const float*)d_in[1];
  const float* emb_T   = (const float*)d_in[2];
  const float* W_ih    = (const float*)d_in[3];
  const float* W_hh    = (const float*)d_in[4];
  const float* b_ih    = (const float*)d_in[5];
  const float* b_hh    = (const float*)d_in[6];
  const float* attn_W1 = (const float*)d_in[7];
  const float* attn_b1 = (const float*)d_in[8];
  const float* attn_v  = (const float*)d_in[9];
  const float* out_W   = (const float*)d_in[10];
  const float* out_b   = (const float*)d_in[11];
  float* out = (float*)d_out;
  char* wsb  = (char*)d_ws;

  hipMemsetAsync(wsb + OFF_BAR, 0, 18432, stream);

  void* args[] = {
    (void*)&hidden, (void*)&emb_src, (void*)&emb_T, (void*)&W_ih, (void*)&W_hh,
    (void*)&b_ih, (void*)&b_hh, (void*)&attn_W1, (void*)&attn_b1, (void*)&attn_v,
    (void*)&out_W, (void*)&out_b, (void*)&out, (void*)&wsb
  };
  hipLaunchCooperativeKernel((void*)k_decoder, dim3(NBLK), dim3(NTHR), args, 0, stream);
}

// Round 15
// 1483.077 us; speedup vs baseline: 1.3607x; 1.1759x over previous
//
#include <hip/hip_runtime.h>
#include <cstddef>
#include <cstdint>

#define LANG 50257
#define EDIM 512
#define HDIM 1024
#define ADIM 512
#define SLEN 1024
#define NSTEP 25
#define TEMPF 10.0f
#define SOSIDX 1
#define VOFF (NSTEP * LANG)
#define NBLK 256
#define NTHR 1024

// ---- ws byte offsets --------------------------------------------------------
#define OFF_W8     0u           // int8 out_W, permuted rows: 53248*1536
#define OFF_SCL    81788928u    // fp32 per-row scale, 53248
#define OFF_EMBTB  82001920u    // int8 emb_T rows: 50257*512
#define OFF_H      135562240u   // 2*1024
#define OFF_HPROJ8 135570432u   // 8*512
#define OFF_EANX8  135586816u   // 8*512
#define OFF_ATTN8  135603200u   // 8*512
#define OFF_DENWP  135619584u   // 256
#define OFF_SDENP  135620608u   // 256
#define OFF_ESCL   135627776u   // fp32 per-row emb scale, 50257
#define OFF_BAR    135831552u   // padded flags: 4608 u32 (memset per launch)

typedef unsigned int v4u __attribute__((ext_vector_type(4)));
typedef unsigned int v2u __attribute__((ext_vector_type(2)));

__device__ __forceinline__ float wred(float x) {
#pragma unroll
  for (int off = 32; off; off >>= 1) x += __shfl_down(x, off);
  return x;
}

// device-scope (coherence-point) accesses, NO cache maintenance
__device__ __forceinline__ unsigned gldu(const unsigned* p) {
  return __hip_atomic_load((unsigned*)p, __ATOMIC_RELAXED, __HIP_MEMORY_SCOPE_AGENT);
}
__device__ __forceinline__ void gstu(unsigned* p, unsigned v) {
  __hip_atomic_store(p, v, __ATOMIC_RELAXED, __HIP_MEMORY_SCOPE_AGENT);
}
__device__ __forceinline__ float gldf(const float* p) {
  return __hip_atomic_load((float*)p, __ATOMIC_RELAXED, __HIP_MEMORY_SCOPE_AGENT);
}
__device__ __forceinline__ void gstf(float* p, float v) {
  __hip_atomic_store(p, v, __ATOMIC_RELAXED, __HIP_MEMORY_SCOPE_AGENT);
}

// Contention-free tree barrier (R13, proven).
__device__ __forceinline__ void gridbar(unsigned* bar, int bid, unsigned round) {
  __syncthreads();
  const int tid = threadIdx.x;
  asm volatile("" ::: "memory");
  if (tid < 64) {
    if (tid == 0) {
      asm volatile("s_waitcnt vmcnt(0) lgkmcnt(0)" ::: "memory");
      gstu(&bar[bid * 16], round);
    }
    if ((bid & 15) == 0) {
      unsigned v;
      for (;;) {
        v = (tid < 16) ? gldu(&bar[(bid + tid) * 16]) : round;
        if (!__any(v < round)) break;
        __builtin_amdgcn_s_sleep(1);
      }
      if (tid == 0) gstu(&bar[4096 + (bid >> 4) * 16], round);
    }
    if (bid == 0) {
      unsigned v;
      for (;;) {
        v = (tid < 16) ? gldu(&bar[4096 + tid * 16]) : round;
        if (!__any(v < round)) break;
        __builtin_amdgcn_s_sleep(1);
      }
      if (tid < 16) gstu(&bar[4352 + tid * 16], round);
    }
    if (tid == 0) {
      while (gldu(&bar[4352 + (bid >> 4) * 16]) < round)
        __builtin_amdgcn_s_sleep(2);
    }
  }
  asm volatile("" ::: "memory");
  __syncthreads();
}

__device__ __forceinline__ void gridbar_f(unsigned* bar, int bid, unsigned round) {
  __syncthreads();
  if (threadIdx.x == 0) __threadfence();
  gridbar(bar, bid, round);
  if (threadIdx.x == 0) __threadfence();
  __syncthreads();
}

// manual async loads (saddr = ws base SGPR pair, 32-bit voffset)
#define GLD4(dst, off)                                                   \
  asm volatile("global_load_dwordx4 %0, %1, %2"                          \
               : "=v"(dst) : "v"(off), "s"(wsb))
#define GLD2(dst, off)                                                   \
  asm volatile("global_load_dwordx2 %0, %1, %2"                          \
               : "=v"(dst) : "v"(off), "s"(wsb))

// int8 dot: byte j of word = column group j (identity layout); acc by ref
#define DOTA(a, w, x0, x1, x2, x3)                                       \
  {                                                                      \
    (a) += (float)((int)((w) << 24) >> 24) * (x0);                       \
    (a) += (float)((int)((w) << 16) >> 24) * (x1);                       \
    (a) += (float)((int)((w) << 8)  >> 24) * (x2);                       \
    (a) += (float)((int)(w) >> 24)          * (x3);                      \
  }

__global__ __launch_bounds__(NTHR, 4) void k_decoder(
    const float* __restrict__ hidden, const float* __restrict__ emb_src,
    const float* __restrict__ emb_T,  const float* __restrict__ W_ih,
    const float* __restrict__ W_hh,   const float* __restrict__ b_ih,
    const float* __restrict__ b_hh,   const float* __restrict__ W1,
    const float* __restrict__ b1,     const float* __restrict__ vvec,
    const float* __restrict__ out_W,  const float* __restrict__ out_b,
    float* __restrict__ out, char* __restrict__ wsb) {
  __shared__ __align__(16) float smem[9776];       // work area
  __shared__ __align__(16) float sWih[6144];       // [4 j][3 g][512]
  __shared__ __align__(16) float sWhh[12288];      // [4 j][3 g][1024]
  __shared__ __align__(16) float sW1h[2048];       // [4 j][512]
  __shared__ __align__(16) float sP[2048];         // [4 s][512]
  __shared__ __align__(16) float sE[2048];         // [4 s][512]
  const int tid = threadIdx.x, bid = blockIdx.x;
  const int wid = tid >> 6, lane = tid & 63;

  float* hws    = (float*)(wsb + OFF_H);
  float* hproj8 = (float*)(wsb + OFF_HPROJ8);
  float* eanx8  = (float*)(wsb + OFF_EANX8);
  float* attn8  = (float*)(wsb + OFF_ATTN8);
  float* denwp  = (float*)(wsb + OFF_DENWP);
  float* sdenp  = (float*)(wsb + OFF_SDENP);
  float* scl    = (float*)(wsb + OFF_SCL);
  float* escl   = (float*)(wsb + OFF_ESCL);
  unsigned* bar = (unsigned*)(wsb + OFF_BAR);
  unsigned rnd = 0;

  // ================= pre-phase (R14, unchanged) =============================
  {
    uint2* w8w = (uint2*)(wsb + OFF_W8);
    const float4* src = (const float4*)out_W;
    int gw = bid * 16 + wid;
    for (int r = 0; r < 13; ++r) {
      int l = gw + r * 4096;
      if (r < 12 || l < LANG) {
        int p = gw * 13 + r;
        float4 f[6];
#pragma unroll
        for (int k = 0; k < 3; ++k) {
          f[2 * k]     = src[(size_t)l * 384 + k * 128 + lane * 2];
          f[2 * k + 1] = src[(size_t)l * 384 + k * 128 + lane * 2 + 1];
        }
        float mx = 0.f;
#pragma unroll
        for (int k = 0; k < 6; ++k)
          mx = fmaxf(mx, fmaxf(fmaxf(fabsf(f[k].x), fabsf(f[k].y)),
                               fmaxf(fabsf(f[k].z), fabsf(f[k].w))));
#pragma unroll
        for (int off = 32; off; off >>= 1) mx = fmaxf(mx, __shfl_down(mx, off));
        mx = __shfl(mx, 0);
        float inv = (mx > 0.f) ? 127.f / mx : 0.f;
#pragma unroll
        for (int k = 0; k < 3; ++k) {
          unsigned ux = 0, uy = 0;
          ux |= ((unsigned)((int)rintf(f[2*k].x * inv) & 255));
          ux |= ((unsigned)((int)rintf(f[2*k].y * inv) & 255)) << 8;
          ux |= ((unsigned)((int)rintf(f[2*k].z * inv) & 255)) << 16;
          ux |= ((unsigned)((int)rintf(f[2*k].w * inv) & 255)) << 24;
          uy |= ((unsigned)((int)rintf(f[2*k+1].x * inv) & 255));
          uy |= ((unsigned)((int)rintf(f[2*k+1].y * inv) & 255)) << 8;
          uy |= ((unsigned)((int)rintf(f[2*k+1].z * inv) & 255)) << 16;
          uy |= ((unsigned)((int)rintf(f[2*k+1].w * inv) & 255)) << 24;
          w8w[(size_t)p * 192 + k * 64 + lane] = make_uint2(ux, uy);
        }
        if (lane == 0) scl[p] = (mx > 0.f) ? mx / 127.f : 0.f;
      } else {
        int p = gw * 13 + r;
#pragma unroll
        for (int k = 0; k < 3; ++k)
          w8w[(size_t)p * 192 + k * 64 + lane] = make_uint2(0u, 0u);
        if (lane == 0) scl[p] = 0.f;
      }
    }
    // emb_T -> int8 per-row scale
    {
      uint2* e8w = (uint2*)(wsb + OFF_EMBTB);
      for (int l = gw; l < LANG; l += 4096) {
        const float4* er = (const float4*)(emb_T + (size_t)l * 512);
        float4 f0 = er[lane * 2], f1 = er[lane * 2 + 1];
        float mx = fmaxf(fmaxf(fmaxf(fabsf(f0.x), fabsf(f0.y)),
                               fmaxf(fabsf(f0.z), fabsf(f0.w))),
                         fmaxf(fmaxf(fabsf(f1.x), fabsf(f1.y)),
                               fmaxf(fabsf(f1.z), fabsf(f1.w))));
#pragma unroll
        for (int off = 32; off; off >>= 1) mx = fmaxf(mx, __shfl_down(mx, off));
        mx = __shfl(mx, 0);
        float inv = (mx > 0.f) ? 127.f / mx : 0.f;
        unsigned ux = 0, uy = 0;
        ux |= ((unsigned)((int)rintf(f0.x * inv) & 255));
        ux |= ((unsigned)((int)rintf(f0.y * inv) & 255)) << 8;
        ux |= ((unsigned)((int)rintf(f0.z * inv) & 255)) << 16;
        ux |= ((unsigned)((int)rintf(f0.w * inv) & 255)) << 24;
        uy |= ((unsigned)((int)rintf(f1.x * inv) & 255));
        uy |= ((unsigned)((int)rintf(f1.y * inv) & 255)) << 8;
        uy |= ((unsigned)((int)rintf(f1.z * inv) & 255)) << 16;
        uy |= ((unsigned)((int)rintf(f1.w * inv) & 255)) << 24;
        e8w[(size_t)l * 64 + lane] = make_uint2(ux, uy);
        if (lane == 0) escl[l] = (mx > 0.f) ? mx / 127.f : 0.f;
      }
    }
    // persistent LDS fills
    for (int i = tid; i < 2048; i += NTHR)
      sE[i] = emb_src[(size_t)bid * 2048 + i];
    for (int i = tid; i < 6144; i += NTHR) {
      int jl = i / 1536, rem = i % 1536, g = rem >> 9, e = rem & 511;
      sWih[i] = W_ih[(size_t)(bid * 4 + jl + g * HDIM) * EDIM + e];
    }
    for (int i = tid; i < 12288; i += NTHR) {
      int jl = i / 3072, rem = i % 3072, g = rem >> 10, e = rem & 1023;
      sWhh[i] = W_hh[(size_t)(bid * 4 + jl + g * HDIM) * HDIM + e];
    }
    for (int i = tid; i < 2048; i += NTHR) {
      int jl = i >> 9, a = i & 511;
      sW1h[i] = W1[(size_t)(ADIM + bid * 4 + jl) * ADIM + a];
    }
    __syncthreads();
    if (tid < ADIM) {
      float bb = b1[tid];
      float a0 = bb, a1 = bb, a2 = bb, a3 = bb;
      for (int k = 0; k < ADIM; ++k) {
        float w = W1[(size_t)k * ADIM + tid];
        a0 += sE[k] * w; a1 += sE[512 + k] * w;
        a2 += sE[1024 + k] * w; a3 += sE[1536 + k] * w;
      }
      sP[tid] = a0; sP[512 + tid] = a1; sP[1024 + tid] = a2; sP[1536 + tid] = a3;
    }
    if (bid == 0) {
      for (int i = tid; i < 8 * EDIM; i += NTHR)
        eanx8[i] = (i < EDIM) ? emb_T[(size_t)SOSIDX * EDIM + i] : 0.f;
      if (tid < 256) denwp[tid] = (tid == 0) ? 1.0f : 0.0f;
    }
    if (bid == 1) { for (int i = tid; i < 8 * ADIM; i += NTHR) hproj8[i] = 0.f; }
    if (bid == 2) { hws[tid] = hidden[tid]; }
    if (bid == 3) { for (int i = tid; i < 8 * ADIM; i += NTHR) attn8[i] = 0.f; }
  }
  rnd++; gridbar_f(bar, bid, rnd);

  for (int t = 0; t < NSTEP; ++t) {
    const int cur = t & 1, nxt = cur ^ 1;
    float* hold = hws + cur * HDIM;
    float* hnew = hws + nxt * HDIM;

    // ==== X: GRU (LDS weights) + hproj scatter (+ zero attn8) ===============
    {
      float easum = 0.f;
      if (tid < EDIM) {
#pragma unroll
        for (int k = 0; k < 8; ++k) easum += gldf(&eanx8[k * EDIM + tid]);
      }
      float dp = 0.f;
      if (tid >= 512 && tid < 768) dp = gldf(&denwp[tid - 512]);
      smem[512 + tid] = gldf(&hold[tid]);
      if (bid < 8 && tid < ADIM) gstf(&attn8[bid * ADIM + tid], 0.f);
      dp = wred(dp);
      if (tid >= 512 && tid < 768 && lane == 0) smem[1632 + (wid - 8)] = dp;
      __syncthreads();
      float inv = 1.0f / (smem[1632] + smem[1633] + smem[1634] + smem[1635]);
      if (tid < EDIM) smem[tid] = easum * inv;
      __syncthreads();

      int jl = wid & 3, part = wid >> 2;
      float ir = 0.f, iz = 0.f, in_ = 0.f;
#pragma unroll
      for (int k = 0; k < 2; ++k) {
        int e = part * 128 + k * 64 + lane;
        float x = smem[e];
        ir  += sWih[jl * 1536 + e] * x;
        iz  += sWih[jl * 1536 + 512 + e] * x;
        in_ += sWih[jl * 1536 + 1024 + e] * x;
      }
      float hr = 0.f, hz = 0.f, hn = 0.f;
#pragma unroll
      for (int k = 0; k < 4; ++k) {
        int e = part * 256 + k * 64 + lane;
        float x = smem[512 + e];
        hr += sWhh[jl * 3072 + e] * x;
        hz += sWhh[jl * 3072 + 1024 + e] * x;
        hn += sWhh[jl * 3072 + 2048 + e] * x;
      }
#pragma unroll
      for (int off = 32; off; off >>= 1) {
        ir += __shfl_down(ir, off);  iz += __shfl_down(iz, off);  in_ += __shfl_down(in_, off);
        hr += __shfl_down(hr, off);  hz += __shfl_down(hz, off);  hn += __shfl_down(hn, off);
      }
      if (lane == 0) {
        float* pb = smem + 1536 + (jl * 4 + part) * 6;
        pb[0] = ir; pb[1] = iz; pb[2] = in_; pb[3] = hr; pb[4] = hz; pb[5] = hn;
      }
      __syncthreads();
      if (tid < 4) {
        int jj = bid * 4 + tid;
        float sir = 0.f, siz = 0.f, sin_ = 0.f, shr = 0.f, shz = 0.f, shn = 0.f;
#pragma unroll
        for (int p = 0; p < 4; ++p) {
          float* pb = smem + 1536 + (tid * 4 + p) * 6;
          sir += pb[0]; siz += pb[1]; sin_ += pb[2];
          shr += pb[3]; shz += pb[4]; shn += pb[5];
        }
        float r = 1.f / (1.f + expf(-(sir + b_ih[jj] + shr + b_hh[jj])));
        float z = 1.f / (1.f + expf(-(siz + b_ih[jj + HDIM] + shz + b_hh[jj + HDIM])));
        float n = tanhf(sin_ + b_ih[jj + 2 * HDIM] + r * (shn + b_hh[jj + 2 * HDIM]));
        float hv = (1.f - z) * n + z * smem[512 + jj];
        gstf(&hnew[jj], hv);
        smem[1640 + tid] = hv;
      }
      __syncthreads();
      if (tid < ADIM) {
        float s = 0.f;
#pragma unroll
        for (int jl2 = 0; jl2 < 4; ++jl2)
          s += smem[1640 + jl2] * sW1h[jl2 * 512 + tid];
        atomicAdd(&hproj8[(bid & 7) * ADIM + tid], s);
      }
    }
    rnd++; gridbar(bar, bid, rnd);

    // ==== Y: scores (LDS P) + sdenp + attn partials (+ zero eanx8) ==========
    {
      float hp = 0.f;
      if (tid < ADIM) {
#pragma unroll
        for (int k = 0; k < 8; ++k) hp += gldf(&hproj8[k * ADIM + tid]);
      }
      if (tid >= 512) smem[tid] = vvec[tid - 512];
      if (tid < ADIM) smem[tid] = hp;
      if (bid < 8 && tid < EDIM) gstf(&eanx8[bid * EDIM + tid], 0.f);
      __syncthreads();
      int sl = wid & 3, part = wid >> 2;
      float acc = 0.f;
#pragma unroll
      for (int k = 0; k < 2; ++k) {
        int a = part * 128 + k * 64 + lane;
        acc += smem[512 + a] * tanhf(sP[sl * 512 + a] + smem[a]);
      }
      acc = wred(acc);
      if (lane == 0) smem[1024 + wid] = acc;
      __syncthreads();
      if (tid < 4) {
        float tot = smem[1024 + tid] + smem[1028 + tid] + smem[1032 + tid] + smem[1036 + tid];
        float e = expf(tot);
        smem[1040 + tid] = e;
        smem[9764 + tid] = e;
      }
      __syncthreads();
      if (tid == 0)
        gstf(&sdenp[bid], smem[1040] + smem[1041] + smem[1042] + smem[1043]);
      if (tid < ADIM) {
        float pa = smem[1040] * sE[tid] + smem[1041] * sE[512 + tid]
                 + smem[1042] * sE[1024 + tid] + smem[1043] * sE[1536 + tid];
        atomicAdd(&attn8[(bid & 7) * ADIM + tid], pa);
      }
    }
    rnd++; gridbar(bar, bid, rnd);

    // ==== Z: counted-vmcnt asm pipeline, fused logits + feedback ============
    {
      float sp = 0.f;
      if (tid >= 512 && tid < 768) sp = gldf(&sdenp[tid - 512]);
      smem[tid] = gldf(&hnew[tid]);
      float a8 = 0.f;
      if (tid < ADIM) {
#pragma unroll
        for (int k = 0; k < 8; ++k) a8 += gldf(&attn8[k * ADIM + tid]);
      }
      if (bid < 8 && tid < ADIM) gstf(&hproj8[bid * ADIM + tid], 0.f);
      sp = wred(sp);
      if (tid >= 512 && tid < 768 && lane == 0) smem[9760 + (wid - 8)] = sp;
      __syncthreads();
      float sden_t = smem[9760] + smem[9761] + smem[9762] + smem[9763];
      if (tid < ADIM) smem[HDIM + tid] = a8 / sden_t;
      if (tid >= 1020)
        out[VOFF + (size_t)t * SLEN + bid * 4 + (tid - 1020)] = smem[9764 + tid - 1020] / sden_t;
      __syncthreads();
      const float4* sm4 = (const float4*)smem;
      float xr[24];
#pragma unroll
      for (int k = 0; k < 4; ++k) {
        float4 f = sm4[lane * 4 + k];
        xr[k * 4 + 0] = f.x; xr[k * 4 + 1] = f.y; xr[k * 4 + 2] = f.z; xr[k * 4 + 3] = f.w;
      }
#pragma unroll
      for (int k = 0; k < 2; ++k) {
        float4 f = sm4[256 + lane * 2 + k];
        xr[16 + k * 4 + 0] = f.x; xr[16 + k * 4 + 1] = f.y;
        xr[16 + k * 4 + 2] = f.z; xr[16 + k * 4 + 3] = f.w;
      }
      int gw = bid * 16 + wid;
      float myscl = 0.f, myob = 0.f, myes = 0.f;
      if (lane < 13) {
        myscl = scl[gw * 13 + lane];
        int l0 = gw + lane * 4096;
        if (l0 < LANG) { myob = out_b[l0]; myes = escl[l0]; }
      }
      __syncthreads();                  // xr in regs; smem[0..656) reusable
      float* vsl = smem;                // 16*13 vv stash (LDS, not vmcnt)
      const bool fb = (t + 1 < NSTEP);
      float dsum = 0.f;
      float ae[8] = {0.f, 0.f, 0.f, 0.f, 0.f, 0.f, 0.f, 0.f};
      uint32_t o4 = OFF_W8 + (uint32_t)gw * 19968u + (uint32_t)lane * 16u;
      uint32_t o2 = OFF_W8 + (uint32_t)gw * 19968u + 1024u + (uint32_t)lane * 8u;
      uint32_t oe = OFF_EMBTB + (uint32_t)gw * 512u + (uint32_t)lane * 8u;
      v4u q4[2]; v2u q2[2]; v2u e2[2];
      GLD4(q4[0], o4);           GLD2(q2[0], o2);           GLD2(e2[0], oe);
      GLD4(q4[1], o4 + 1536u);   GLD2(q2[1], o2 + 1536u);   GLD2(e2[1], oe + 2097152u);
#pragma unroll
      for (int r = 0; r < 13; ++r) {
        if (r < 12) { asm volatile("s_waitcnt vmcnt(3)" ::: "memory"); }
        else        { asm volatile("s_waitcnt vmcnt(0)" ::: "memory"); }
        __builtin_amdgcn_sched_barrier(0);
        v4u c4 = q4[r & 1]; v2u c2 = q2[r & 1]; v2u ce = e2[r & 1];
        if (r + 2 < 13) {
          GLD4(q4[r & 1], o4 + (uint32_t)(r + 2) * 1536u);
          GLD2(q2[r & 1], o2 + (uint32_t)(r + 2) * 1536u);
          GLD2(e2[r & 1], oe + (uint32_t)(r + 2) * 2097152u);
        }
        float ac0 = 0.f, ac1 = 0.f, ac2 = 0.f, ac3 = 0.f;
        DOTA(ac0, c4[0], xr[0], xr[1], xr[2], xr[3]);
        DOTA(ac1, c4[1], xr[4], xr[5], xr[6], xr[7]);
        DOTA(ac2, c4[2], xr[8], xr[9], xr[10], xr[11]);
        DOTA(ac3, c4[3], xr[12], xr[13], xr[14], xr[15]);
        DOTA(ac0, c2[0], xr[16], xr[17], xr[18], xr[19]);
        DOTA(ac1, c2[1], xr[20], xr[21], xr[22], xr[23]);
        float acc = (ac0 + ac1) + (ac2 + ac3);
        acc = wred(acc);
        float bc = __shfl(acc, 0);
        float sca = __shfl(myscl, r);
        float ob  = __shfl(myob, r);
        float es  = __shfl(myes, r);
        const bool valid = (r < 12) || (gw < LANG - 49152);
        float vv = (bc * sca + ob) * TEMPF;
        if (lane == 0) vsl[wid * 13 + r] = vv;
        if (fb) {
          float ev = valid ? expf(vv) : 0.f;
          dsum += ev;
          float w = ev * es;
          ae[0] += w * (float)((int)(ce[0] << 24) >> 24);
          ae[1] += w * (float)((int)(ce[0] << 16) >> 24);
          ae[2] += w * (float)((int)(ce[0] << 8)  >> 24);
          ae[3] += w * (float)((int)ce[0] >> 24);
          ae[4] += w * (float)((int)(ce[1] << 24) >> 24);
          ae[5] += w * (float)((int)(ce[1] << 16) >> 24);
          ae[6] += w * (float)((int)(ce[1] << 8)  >> 24);
          ae[7] += w * (float)((int)ce[1] >> 24);
        }
      }
      if (lane == 0) smem[640 + wid] = dsum;
      __syncthreads();
      // vout stores from vsl (post-loop: keeps loop vmcnt-pure)
      {
        float* vout = out + (size_t)t * LANG;
        if (tid < 208) {
          int w2 = tid / 13, r2 = tid % 13;
          int l = bid * 16 + w2 + r2 * 4096;
          if (r2 < 12 || (bid * 16 + w2) < LANG - 49152)
            vout[l] = vsl[w2 * 13 + r2];
        }
      }
      if (fb) {
        if (tid == 0) {
          float tot = 0.f;
#pragma unroll
          for (int p = 0; p < 16; ++p) tot += smem[640 + p];
          gstf(&denwp[bid], tot);
        }
        float* big = smem + 1536;
#pragma unroll
        for (int i = 0; i < 8; ++i) big[wid * 512 + i * 64 + lane] = ae[i];
        __syncthreads();
#pragma unroll
        for (int st = 8; st; st >>= 1) {
          for (int i = tid; i < st * 512; i += NTHR) big[i] += big[i + st * 512];
          __syncthreads();
        }
        if (tid < 512) {
          int dim = ((tid & 63) << 3) | (tid >> 6);
          atomicAdd(&eanx8[(bid & 7) * EDIM + dim], big[tid]);
        }
      }
    }
    rnd++; gridbar(bar, bid, rnd);
  }
}

extern "C" void kernel_launch(void* const* d_in, const int* in_sizes, int n_in,
                              void* d_out, int out_size, void* d_ws, size_t ws_size,
                              hipStream_t stream) {
  const float* hidden  = (const float*)d_in[0];
  const float* emb_src = (const float*)d_in[1];
  const float* emb_T   = (const float*)d_in[2];
  const float* W_ih    = (const float*)d_in[3];
  const float* W_hh    = (const float*)d_in[4];
  const float* b_ih    = (const float*)d_in[5];
  const float* b_hh    = (const float*)d_in[6];
  const float* attn_W1 = (const float*)d_in[7];
  const float* attn_b1 = (const float*)d_in[8];
  const float* attn_v  = (const float*)d_in[9];
  const float* out_W   = (const float*)d_in[10];
  const float* out_b   = (const float*)d_in[11];
  float* out = (float*)d_out;
  char* wsb  = (char*)d_ws;

  hipMemsetAsync(wsb + OFF_BAR, 0, 18432, stream);

  void* args[] = {
    (void*)&hidden, (void*)&emb_src, (void*)&emb_T, (void*)&W_ih, (void*)&W_hh,
    (void*)&b_ih, (void*)&b_hh, (void*)&attn_W1, (void*)&attn_b1, (void*)&attn_v,
    (void*)&out_W, (void*)&out_b, (void*)&out, (void*)&wsb
  };
  hipLaunchCooperativeKernel((void*)k_decoder, dim3(NBLK), dim3(NTHR), args, 0, stream);
}

// Round 16
// 1450.853 us; speedup vs baseline: 1.3909x; 1.0222x over previous
//
#include <hip/hip_runtime.h>
#include <cstddef>
#include <cstdint>

#define LANG 50257
#define EDIM 512
#define HDIM 1024
#define ADIM 512
#define SLEN 1024
#define NSTEP 25
#define TEMPF 10.0f
#define SOSIDX 1
#define VOFF (NSTEP * LANG)
#define NBLK 256
#define NTHR 1024

// ---- ws byte offsets --------------------------------------------------------
#define OFF_W8     0u           // int8 out_W, permuted rows: 53248*1536
#define OFF_SCL    81788928u    // fp32 per-row scale, 53248
#define OFF_EMBTB  82001920u    // int8 emb_T rows: 50257*512
#define OFF_H      135562240u   // 2*1024
#define OFF_HPROJ8 135570432u   // 8*512
#define OFF_EANX8  135586816u   // 8*512
#define OFF_ATTN8  135603200u   // 8*512
#define OFF_DENWP  135619584u   // 256
#define OFF_SDENP  135620608u   // 256
#define OFF_ESCL   135627776u   // fp32 per-row emb scale, 50257
#define OFF_BAR    135831552u   // padded flags: 4608 u32 (memset per launch)

typedef unsigned int v4u __attribute__((ext_vector_type(4)));
typedef unsigned int v2u __attribute__((ext_vector_type(2)));

__device__ __forceinline__ float wred(float x) {
#pragma unroll
  for (int off = 32; off; off >>= 1) x += __shfl_down(x, off);
  return x;
}

// device-scope (coherence-point) accesses, NO cache maintenance
__device__ __forceinline__ unsigned gldu(const unsigned* p) {
  return __hip_atomic_load((unsigned*)p, __ATOMIC_RELAXED, __HIP_MEMORY_SCOPE_AGENT);
}
__device__ __forceinline__ void gstu(unsigned* p, unsigned v) {
  __hip_atomic_store(p, v, __ATOMIC_RELAXED, __HIP_MEMORY_SCOPE_AGENT);
}
__device__ __forceinline__ float gldf(const float* p) {
  return __hip_atomic_load((float*)p, __ATOMIC_RELAXED, __HIP_MEMORY_SCOPE_AGENT);
}
__device__ __forceinline__ void gstf(float* p, float v) {
  __hip_atomic_store(p, v, __ATOMIC_RELAXED, __HIP_MEMORY_SCOPE_AGENT);
}

// Contention-free tree barrier (R13, proven).
__device__ __forceinline__ void gridbar(unsigned* bar, int bid, unsigned round) {
  __syncthreads();
  const int tid = threadIdx.x;
  asm volatile("" ::: "memory");
  if (tid < 64) {
    if (tid == 0) {
      asm volatile("s_waitcnt vmcnt(0) lgkmcnt(0)" ::: "memory");
      gstu(&bar[bid * 16], round);
    }
    if ((bid & 15) == 0) {
      unsigned v;
      for (;;) {
        v = (tid < 16) ? gldu(&bar[(bid + tid) * 16]) : round;
        if (!__any(v < round)) break;
        __builtin_amdgcn_s_sleep(1);
      }
      if (tid == 0) gstu(&bar[4096 + (bid >> 4) * 16], round);
    }
    if (bid == 0) {
      unsigned v;
      for (;;) {
        v = (tid < 16) ? gldu(&bar[4096 + tid * 16]) : round;
        if (!__any(v < round)) break;
        __builtin_amdgcn_s_sleep(1);
      }
      if (tid < 16) gstu(&bar[4352 + tid * 16], round);
    }
    if (tid == 0) {
      while (gldu(&bar[4352 + (bid >> 4) * 16]) < round)
        __builtin_amdgcn_s_sleep(2);
    }
  }
  asm volatile("" ::: "memory");
  __syncthreads();
}

__device__ __forceinline__ void gridbar_f(unsigned* bar, int bid, unsigned round) {
  __syncthreads();
  if (threadIdx.x == 0) __threadfence();
  gridbar(bar, bid, round);
  if (threadIdx.x == 0) __threadfence();
  __syncthreads();
}

// manual async loads (saddr = ws base SGPR pair, 32-bit voffset)
#define GLD4(dst, off)                                                   \
  asm volatile("global_load_dwordx4 %0, %1, %2"                          \
               : "=v"(dst) : "v"(off), "s"(wsb))
#define GLD2(dst, off)                                                   \
  asm volatile("global_load_dwordx2 %0, %1, %2"                          \
               : "=v"(dst) : "v"(off), "s"(wsb))

// int8 dot: byte j of word = column group j (identity layout); acc by ref
#define DOTA(a, w, x0, x1, x2, x3)                                       \
  {                                                                      \
    (a) += (float)((int)((w) << 24) >> 24) * (x0);                       \
    (a) += (float)((int)((w) << 16) >> 24) * (x1);                       \
    (a) += (float)((int)((w) << 8)  >> 24) * (x2);                       \
    (a) += (float)((int)(w) >> 24)          * (x3);                      \
  }

// quantize one row (6 float4 in f[]) given wave-reduced mx -> store
__device__ __forceinline__ void quant_row(uint2* w8w, float* scl, int p,
                                          const float4* f, float mx, int lane) {
  float inv = (mx > 0.f) ? 127.f / mx : 0.f;
#pragma unroll
  for (int k = 0; k < 3; ++k) {
    unsigned ux = 0, uy = 0;
    ux |= ((unsigned)((int)rintf(f[2*k].x * inv) & 255));
    ux |= ((unsigned)((int)rintf(f[2*k].y * inv) & 255)) << 8;
    ux |= ((unsigned)((int)rintf(f[2*k].z * inv) & 255)) << 16;
    ux |= ((unsigned)((int)rintf(f[2*k].w * inv) & 255)) << 24;
    uy |= ((unsigned)((int)rintf(f[2*k+1].x * inv) & 255));
    uy |= ((unsigned)((int)rintf(f[2*k+1].y * inv) & 255)) << 8;
    uy |= ((unsigned)((int)rintf(f[2*k+1].z * inv) & 255)) << 16;
    uy |= ((unsigned)((int)rintf(f[2*k+1].w * inv) & 255)) << 24;
    w8w[(size_t)p * 192 + k * 64 + lane] = make_uint2(ux, uy);
  }
  if (lane == 0) scl[p] = (mx > 0.f) ? mx / 127.f : 0.f;
}

__device__ __forceinline__ float rowmax6(const float4* f) {
  float mx = 0.f;
#pragma unroll
  for (int k = 0; k < 6; ++k)
    mx = fmaxf(mx, fmaxf(fmaxf(fabsf(f[k].x), fabsf(f[k].y)),
                         fmaxf(fabsf(f[k].z), fabsf(f[k].w))));
  return mx;
}

__global__ __launch_bounds__(NTHR, 4) void k_decoder(
    const float* __restrict__ hidden, const float* __restrict__ emb_src,
    const float* __restrict__ emb_T,  const float* __restrict__ W_ih,
    const float* __restrict__ W_hh,   const float* __restrict__ b_ih,
    const float* __restrict__ b_hh,   const float* __restrict__ W1,
    const float* __restrict__ b1,     const float* __restrict__ vvec,
    const float* __restrict__ out_W,  const float* __restrict__ out_b,
    float* __restrict__ out, char* __restrict__ wsb) {
  __shared__ __align__(16) float smem[9776];       // work area
  __shared__ __align__(16) float sWih[6144];       // [4 j][3 g][512]
  __shared__ __align__(16) float sWhh[12288];      // [4 j][3 g][1024]
  __shared__ __align__(16) float sW1h[2048];       // [4 j][512]
  __shared__ __align__(16) float sP[2048];         // [4 s][512]
  __shared__ __align__(16) float sE[2048];         // [4 s][512]
  const int tid = threadIdx.x, bid = blockIdx.x;
  const int wid = tid >> 6, lane = tid & 63;

  float* hws    = (float*)(wsb + OFF_H);
  float* hproj8 = (float*)(wsb + OFF_HPROJ8);
  float* eanx8  = (float*)(wsb + OFF_EANX8);
  float* attn8  = (float*)(wsb + OFF_ATTN8);
  float* denwp  = (float*)(wsb + OFF_DENWP);
  float* sdenp  = (float*)(wsb + OFF_SDENP);
  float* scl    = (float*)(wsb + OFF_SCL);
  float* escl   = (float*)(wsb + OFF_ESCL);
  unsigned* bar = (unsigned*)(wsb + OFF_BAR);
  unsigned rnd = 0;

  // ================= pre-phase ==============================================
  {
    uint2* w8w = (uint2*)(wsb + OFF_W8);
    const float4* src = (const float4*)out_W;
    int gw = bid * 16 + wid;
    // rows 0..11: unconditionally valid -> paired (12 float4 in flight)
    for (int r = 0; r < 12; r += 2) {
      int l0 = gw + r * 4096, l1 = gw + (r + 1) * 4096;
      float4 f[6], g[6];
#pragma unroll
      for (int k = 0; k < 3; ++k) {
        f[2 * k]     = src[(size_t)l0 * 384 + k * 128 + lane * 2];
        f[2 * k + 1] = src[(size_t)l0 * 384 + k * 128 + lane * 2 + 1];
        g[2 * k]     = src[(size_t)l1 * 384 + k * 128 + lane * 2];
        g[2 * k + 1] = src[(size_t)l1 * 384 + k * 128 + lane * 2 + 1];
      }
      float mf = rowmax6(f), mg = rowmax6(g);
#pragma unroll
      for (int off = 32; off; off >>= 1) {
        mf = fmaxf(mf, __shfl_down(mf, off));
        mg = fmaxf(mg, __shfl_down(mg, off));
      }
      mf = __shfl(mf, 0); mg = __shfl(mg, 0);
      quant_row(w8w, scl, gw * 13 + r, f, mf, lane);
      quant_row(w8w, scl, gw * 13 + r + 1, g, mg, lane);
    }
    // row 12: guarded (valid only for gw < LANG-49152), else zero-fill
    {
      int r = 12, l = gw + r * 4096, p = gw * 13 + r;
      if (l < LANG) {
        float4 f[6];
#pragma unroll
        for (int k = 0; k < 3; ++k) {
          f[2 * k]     = src[(size_t)l * 384 + k * 128 + lane * 2];
          f[2 * k + 1] = src[(size_t)l * 384 + k * 128 + lane * 2 + 1];
        }
        float mx = rowmax6(f);
#pragma unroll
        for (int off = 32; off; off >>= 1) mx = fmaxf(mx, __shfl_down(mx, off));
        mx = __shfl(mx, 0);
        quant_row(w8w, scl, p, f, mx, lane);
      } else {
#pragma unroll
        for (int k = 0; k < 3; ++k)
          w8w[(size_t)p * 192 + k * 64 + lane] = make_uint2(0u, 0u);
        if (lane == 0) scl[p] = 0.f;
      }
    }
    // emb_T -> int8 per-row scale (paired)
    {
      uint2* e8w = (uint2*)(wsb + OFF_EMBTB);
      int nv = (gw < LANG - 49152) ? 13 : 12;   // valid rows at stride 4096
      int k2 = 0;
      for (; k2 + 1 < nv; k2 += 2) {
        int l0 = gw + k2 * 4096, l1 = l0 + 4096;
        const float4* er0 = (const float4*)(emb_T + (size_t)l0 * 512);
        const float4* er1 = (const float4*)(emb_T + (size_t)l1 * 512);
        float4 f0 = er0[lane * 2], f1 = er0[lane * 2 + 1];
        float4 g0 = er1[lane * 2], g1 = er1[lane * 2 + 1];
        float mf = fmaxf(fmaxf(fmaxf(fabsf(f0.x), fabsf(f0.y)),
                               fmaxf(fabsf(f0.z), fabsf(f0.w))),
                         fmaxf(fmaxf(fabsf(f1.x), fabsf(f1.y)),
                               fmaxf(fabsf(f1.z), fabsf(f1.w))));
        float mg = fmaxf(fmaxf(fmaxf(fabsf(g0.x), fabsf(g0.y)),
                               fmaxf(fabsf(g0.z), fabsf(g0.w))),
                         fmaxf(fmaxf(fabsf(g1.x), fabsf(g1.y)),
                               fmaxf(fabsf(g1.z), fabsf(g1.w))));
#pragma unroll
        for (int off = 32; off; off >>= 1) {
          mf = fmaxf(mf, __shfl_down(mf, off));
          mg = fmaxf(mg, __shfl_down(mg, off));
        }
        mf = __shfl(mf, 0); mg = __shfl(mg, 0);
        float invf = (mf > 0.f) ? 127.f / mf : 0.f;
        float invg = (mg > 0.f) ? 127.f / mg : 0.f;
        unsigned ux, uy;
        ux  = ((unsigned)((int)rintf(f0.x * invf) & 255));
        ux |= ((unsigned)((int)rintf(f0.y * invf) & 255)) << 8;
        ux |= ((unsigned)((int)rintf(f0.z * invf) & 255)) << 16;
        ux |= ((unsigned)((int)rintf(f0.w * invf) & 255)) << 24;
        uy  = ((unsigned)((int)rintf(f1.x * invf) & 255));
        uy |= ((unsigned)((int)rintf(f1.y * invf) & 255)) << 8;
        uy |= ((unsigned)((int)rintf(f1.z * invf) & 255)) << 16;
        uy |= ((unsigned)((int)rintf(f1.w * invf) & 255)) << 24;
        e8w[(size_t)l0 * 64 + lane] = make_uint2(ux, uy);
        ux  = ((unsigned)((int)rintf(g0.x * invg) & 255));
        ux |= ((unsigned)((int)rintf(g0.y * invg) & 255)) << 8;
        ux |= ((unsigned)((int)rintf(g0.z * invg) & 255)) << 16;
        ux |= ((unsigned)((int)rintf(g0.w * invg) & 255)) << 24;
        uy  = ((unsigned)((int)rintf(g1.x * invg) & 255));
        uy |= ((unsigned)((int)rintf(g1.y * invg) & 255)) << 8;
        uy |= ((unsigned)((int)rintf(g1.z * invg) & 255)) << 16;
        uy |= ((unsigned)((int)rintf(g1.w * invg) & 255)) << 24;
        e8w[(size_t)l1 * 64 + lane] = make_uint2(ux, uy);
        if (lane == 0) {
          escl[l0] = (mf > 0.f) ? mf / 127.f : 0.f;
          escl[l1] = (mg > 0.f) ? mg / 127.f : 0.f;
        }
      }
      if (k2 < nv) {
        int l = gw + k2 * 4096;
        const float4* er = (const float4*)(emb_T + (size_t)l * 512);
        float4 f0 = er[lane * 2], f1 = er[lane * 2 + 1];
        float mx = fmaxf(fmaxf(fmaxf(fabsf(f0.x), fabsf(f0.y)),
                               fmaxf(fabsf(f0.z), fabsf(f0.w))),
                         fmaxf(fmaxf(fabsf(f1.x), fabsf(f1.y)),
                               fmaxf(fabsf(f1.z), fabsf(f1.w))));
#pragma unroll
        for (int off = 32; off; off >>= 1) mx = fmaxf(mx, __shfl_down(mx, off));
        mx = __shfl(mx, 0);
        float inv = (mx > 0.f) ? 127.f / mx : 0.f;
        unsigned ux, uy;
        ux  = ((unsigned)((int)rintf(f0.x * inv) & 255));
        ux |= ((unsigned)((int)rintf(f0.y * inv) & 255)) << 8;
        ux |= ((unsigned)((int)rintf(f0.z * inv) & 255)) << 16;
        ux |= ((unsigned)((int)rintf(f0.w * inv) & 255)) << 24;
        uy  = ((unsigned)((int)rintf(f1.x * inv) & 255));
        uy |= ((unsigned)((int)rintf(f1.y * inv) & 255)) << 8;
        uy |= ((unsigned)((int)rintf(f1.z * inv) & 255)) << 16;
        uy |= ((unsigned)((int)rintf(f1.w * inv) & 255)) << 24;
        e8w[(size_t)l * 64 + lane] = make_uint2(ux, uy);
        if (lane == 0) escl[l] = (mx > 0.f) ? mx / 127.f : 0.f;
      }
    }
    // persistent LDS fills
    for (int i = tid; i < 2048; i += NTHR)
      sE[i] = emb_src[(size_t)bid * 2048 + i];
    for (int i = tid; i < 6144; i += NTHR) {
      int jl = i / 1536, rem = i % 1536, g = rem >> 9, e = rem & 511;
      sWih[i] = W_ih[(size_t)(bid * 4 + jl + g * HDIM) * EDIM + e];
    }
    for (int i = tid; i < 12288; i += NTHR) {
      int jl = i / 3072, rem = i % 3072, g = rem >> 10, e = rem & 1023;
      sWhh[i] = W_hh[(size_t)(bid * 4 + jl + g * HDIM) * HDIM + e];
    }
    for (int i = tid; i < 2048; i += NTHR) {
      int jl = i >> 9, a = i & 511;
      sW1h[i] = W1[(size_t)(ADIM + bid * 4 + jl) * ADIM + a];
    }
    __syncthreads();
    if (tid < ADIM) {
      float bb = b1[tid];
      float a0 = bb, a1 = bb, a2 = bb, a3 = bb;
      for (int k = 0; k < ADIM; ++k) {
        float w = W1[(size_t)k * ADIM + tid];
        a0 += sE[k] * w; a1 += sE[512 + k] * w;
        a2 += sE[1024 + k] * w; a3 += sE[1536 + k] * w;
      }
      sP[tid] = a0; sP[512 + tid] = a1; sP[1024 + tid] = a2; sP[1536 + tid] = a3;
    }
    if (bid == 0) {
      for (int i = tid; i < 8 * EDIM; i += NTHR)
        eanx8[i] = (i < EDIM) ? emb_T[(size_t)SOSIDX * EDIM + i] : 0.f;
      if (tid < 256) denwp[tid] = (tid == 0) ? 1.0f : 0.0f;
    }
    if (bid == 1) { for (int i = tid; i < 8 * ADIM; i += NTHR) hproj8[i] = 0.f; }
    if (bid == 2) { hws[tid] = hidden[tid]; }
    if (bid == 3) { for (int i = tid; i < 8 * ADIM; i += NTHR) attn8[i] = 0.f; }
  }
  rnd++; gridbar_f(bar, bid, rnd);

  for (int t = 0; t < NSTEP; ++t) {
    const int cur = t & 1, nxt = cur ^ 1;
    float* hold = hws + cur * HDIM;
    float* hnew = hws + nxt * HDIM;

    // ==== X: GRU (LDS weights) + hproj scatter (+ zero attn8) ===============
    {
      float easum = 0.f;
      if (tid < EDIM) {
#pragma unroll
        for (int k = 0; k < 8; ++k) easum += gldf(&eanx8[k * EDIM + tid]);
      }
      float dp = 0.f;
      if (tid >= 512 && tid < 768) dp = gldf(&denwp[tid - 512]);
      smem[512 + tid] = gldf(&hold[tid]);
      if (bid < 8 && tid < ADIM) gstf(&attn8[bid * ADIM + tid], 0.f);
      dp = wred(dp);
      if (tid >= 512 && tid < 768 && lane == 0) smem[1632 + (wid - 8)] = dp;
      __syncthreads();
      float inv = 1.0f / (smem[1632] + smem[1633] + smem[1634] + smem[1635]);
      if (tid < EDIM) smem[tid] = easum * inv;
      __syncthreads();

      int jl = wid & 3, part = wid >> 2;
      float ir = 0.f, iz = 0.f, in_ = 0.f;
#pragma unroll
      for (int k = 0; k < 2; ++k) {
        int e = part * 128 + k * 64 + lane;
        float x = smem[e];
        ir  += sWih[jl * 1536 + e] * x;
        iz  += sWih[jl * 1536 + 512 + e] * x;
        in_ += sWih[jl * 1536 + 1024 + e] * x;
      }
      float hr = 0.f, hz = 0.f, hn = 0.f;
#pragma unroll
      for (int k = 0; k < 4; ++k) {
        int e = part * 256 + k * 64 + lane;
        float x = smem[512 + e];
        hr += sWhh[jl * 3072 + e] * x;
        hz += sWhh[jl * 3072 + 1024 + e] * x;
        hn += sWhh[jl * 3072 + 2048 + e] * x;
      }
#pragma unroll
      for (int off = 32; off; off >>= 1) {
        ir += __shfl_down(ir, off);  iz += __shfl_down(iz, off);  in_ += __shfl_down(in_, off);
        hr += __shfl_down(hr, off);  hz += __shfl_down(hz, off);  hn += __shfl_down(hn, off);
      }
      if (lane == 0) {
        float* pb = smem + 1536 + (jl * 4 + part) * 6;
        pb[0] = ir; pb[1] = iz; pb[2] = in_; pb[3] = hr; pb[4] = hz; pb[5] = hn;
      }
      __syncthreads();
      if (tid < 4) {
        int jj = bid * 4 + tid;
        float sir = 0.f, siz = 0.f, sin_ = 0.f, shr = 0.f, shz = 0.f, shn = 0.f;
#pragma unroll
        for (int p = 0; p < 4; ++p) {
          float* pb = smem + 1536 + (tid * 4 + p) * 6;
          sir += pb[0]; siz += pb[1]; sin_ += pb[2];
          shr += pb[3]; shz += pb[4]; shn += pb[5];
        }
        float r = 1.f / (1.f + expf(-(sir + b_ih[jj] + shr + b_hh[jj])));
        float z = 1.f / (1.f + expf(-(siz + b_ih[jj + HDIM] + shz + b_hh[jj + HDIM])));
        float n = tanhf(sin_ + b_ih[jj + 2 * HDIM] + r * (shn + b_hh[jj + 2 * HDIM]));
        float hv = (1.f - z) * n + z * smem[512 + jj];
        gstf(&hnew[jj], hv);
        smem[1640 + tid] = hv;
      }
      __syncthreads();
      if (tid < ADIM) {
        float s = 0.f;
#pragma unroll
        for (int jl2 = 0; jl2 < 4; ++jl2)
          s += smem[1640 + jl2] * sW1h[jl2 * 512 + tid];
        atomicAdd(&hproj8[(bid & 7) * ADIM + tid], s);
      }
    }
    rnd++; gridbar(bar, bid, rnd);

    // ==== Y: scores (LDS P) + sdenp + attn partials (+ zero eanx8) ==========
    {
      float hp = 0.f;
      if (tid < ADIM) {
#pragma unroll
        for (int k = 0; k < 8; ++k) hp += gldf(&hproj8[k * ADIM + tid]);
      }
      if (tid >= 512) smem[tid] = vvec[tid - 512];
      if (tid < ADIM) smem[tid] = hp;
      if (bid < 8 && tid < EDIM) gstf(&eanx8[bid * EDIM + tid], 0.f);
      __syncthreads();
      int sl = wid & 3, part = wid >> 2;
      float acc = 0.f;
#pragma unroll
      for (int k = 0; k < 2; ++k) {
        int a = part * 128 + k * 64 + lane;
        acc += smem[512 + a] * tanhf(sP[sl * 512 + a] + smem[a]);
      }
      acc = wred(acc);
      if (lane == 0) smem[1024 + wid] = acc;
      __syncthreads();
      if (tid < 4) {
        float tot = smem[1024 + tid] + smem[1028 + tid] + smem[1032 + tid] + smem[1036 + tid];
        float e = expf(tot);
        smem[1040 + tid] = e;
        smem[9764 + tid] = e;
      }
      __syncthreads();
      if (tid == 0)
        gstf(&sdenp[bid], smem[1040] + smem[1041] + smem[1042] + smem[1043]);
      if (tid < ADIM) {
        float pa = smem[1040] * sE[tid] + smem[1041] * sE[512 + tid]
                 + smem[1042] * sE[1024 + tid] + smem[1043] * sE[1536 + tid];
        atomicAdd(&attn8[(bid & 7) * ADIM + tid], pa);
      }
    }
    rnd++; gridbar(bar, bid, rnd);

    // ==== Z: depth-3 counted-vmcnt pipeline, fused logits + feedback ========
    {
      float sp = 0.f;
      if (tid >= 512 && tid < 768) sp = gldf(&sdenp[tid - 512]);
      smem[tid] = gldf(&hnew[tid]);
      float a8 = 0.f;
      if (tid < ADIM) {
#pragma unroll
        for (int k = 0; k < 8; ++k) a8 += gldf(&attn8[k * ADIM + tid]);
      }
      if (bid < 8 && tid < ADIM) gstf(&hproj8[bid * ADIM + tid], 0.f);
      sp = wred(sp);
      if (tid >= 512 && tid < 768 && lane == 0) smem[9760 + (wid - 8)] = sp;
      __syncthreads();
      float sden_t = smem[9760] + smem[9761] + smem[9762] + smem[9763];
      if (tid < ADIM) smem[HDIM + tid] = a8 / sden_t;
      if (tid >= 1020)
        out[VOFF + (size_t)t * SLEN + bid * 4 + (tid - 1020)] = smem[9764 + tid - 1020] / sden_t;
      __syncthreads();
      const float4* sm4 = (const float4*)smem;
      float xr[24];
#pragma unroll
      for (int k = 0; k < 4; ++k) {
        float4 f = sm4[lane * 4 + k];
        xr[k * 4 + 0] = f.x; xr[k * 4 + 1] = f.y; xr[k * 4 + 2] = f.z; xr[k * 4 + 3] = f.w;
      }
#pragma unroll
      for (int k = 0; k < 2; ++k) {
        float4 f = sm4[256 + lane * 2 + k];
        xr[16 + k * 4 + 0] = f.x; xr[16 + k * 4 + 1] = f.y;
        xr[16 + k * 4 + 2] = f.z; xr[16 + k * 4 + 3] = f.w;
      }
      int gw = bid * 16 + wid;
      float myscl = 0.f, myob = 0.f, myes = 0.f;
      if (lane < 13) {
        myscl = scl[gw * 13 + lane];
        int l0 = gw + lane * 4096;
        if (l0 < LANG) { myob = out_b[l0]; myes = escl[l0]; }
      }
      __syncthreads();                  // xr in regs; smem[0..656) reusable
      float* vsl = smem;                // 16*13 vv stash (LDS, not vmcnt)
      const bool fb = (t + 1 < NSTEP);
      float dsum = 0.f;
      float ae[8] = {0.f, 0.f, 0.f, 0.f, 0.f, 0.f, 0.f, 0.f};
      uint32_t o4 = OFF_W8 + (uint32_t)gw * 19968u + (uint32_t)lane * 16u;
      uint32_t o2 = OFF_W8 + (uint32_t)gw * 19968u + 1024u + (uint32_t)lane * 8u;
      uint32_t oe = OFF_EMBTB + (uint32_t)gw * 512u + (uint32_t)lane * 8u;
      v4u q4[3]; v2u q2[3]; v2u e2[3];
#pragma unroll
      for (int i = 0; i < 3; ++i) {
        GLD4(q4[i], o4 + (uint32_t)i * 1536u);
        GLD2(q2[i], o2 + (uint32_t)i * 1536u);
        GLD2(e2[i], oe + (uint32_t)i * 2097152u);
      }
#pragma unroll
      for (int r = 0; r < 13; ++r) {
        if (r <= 10)      { asm volatile("s_waitcnt vmcnt(6)" ::: "memory"); }
        else if (r == 11) { asm volatile("s_waitcnt vmcnt(3)" ::: "memory"); }
        else              { asm volatile("s_waitcnt vmcnt(0)" ::: "memory"); }
        __builtin_amdgcn_sched_barrier(0);
        v4u c4 = q4[r % 3]; v2u c2 = q2[r % 3]; v2u ce = e2[r % 3];
        if (r + 3 < 13) {
          GLD4(q4[r % 3], o4 + (uint32_t)(r + 3) * 1536u);
          GLD2(q2[r % 3], o2 + (uint32_t)(r + 3) * 1536u);
          GLD2(e2[r % 3], oe + (uint32_t)(r + 3) * 2097152u);
        }
        float ac0 = 0.f, ac1 = 0.f, ac2 = 0.f, ac3 = 0.f;
        DOTA(ac0, c4[0], xr[0], xr[1], xr[2], xr[3]);
        DOTA(ac1, c4[1], xr[4], xr[5], xr[6], xr[7]);
        DOTA(ac2, c4[2], xr[8], xr[9], xr[10], xr[11]);
        DOTA(ac3, c4[3], xr[12], xr[13], xr[14], xr[15]);
        DOTA(ac0, c2[0], xr[16], xr[17], xr[18], xr[19]);
        DOTA(ac1, c2[1], xr[20], xr[21], xr[22], xr[23]);
        float acc = (ac0 + ac1) + (ac2 + ac3);
        acc = wred(acc);
        float bc = __shfl(acc, 0);
        float sca = __shfl(myscl, r);
        float ob  = __shfl(myob, r);
        float es  = __shfl(myes, r);
        const bool valid = (r < 12) || (gw < LANG - 49152);
        float vv = (bc * sca + ob) * TEMPF;
        if (lane == 0) vsl[wid * 13 + r] = vv;
        if (fb) {
          float ev = valid ? expf(vv) : 0.f;
          dsum += ev;
          float w = ev * es;
          ae[0] += w * (float)((int)(ce[0] << 24) >> 24);
          ae[1] += w * (float)((int)(ce[0] << 16) >> 24);
          ae[2] += w * (float)((int)(ce[0] << 8)  >> 24);
          ae[3] += w * (float)((int)ce[0] >> 24);
          ae[4] += w * (float)((int)(ce[1] << 24) >> 24);
          ae[5] += w * (float)((int)(ce[1] << 16) >> 24);
          ae[6] += w * (float)((int)(ce[1] << 8)  >> 24);
          ae[7] += w * (float)((int)ce[1] >> 24);
        }
      }
      if (lane == 0) smem[640 + wid] = dsum;
      __syncthreads();
      // vout stores from vsl (post-loop: keeps loop vmcnt-pure)
      {
        float* vout = out + (size_t)t * LANG;
        if (tid < 208) {
          int w2 = tid / 13, r2 = tid % 13;
          int l = bid * 16 + w2 + r2 * 4096;
          if (r2 < 12 || (bid * 16 + w2) < LANG - 49152)
            vout[l] = vsl[w2 * 13 + r2];
        }
      }
      if (fb) {
        if (tid == 0) {
          float tot = 0.f;
#pragma unroll
          for (int p = 0; p < 16; ++p) tot += smem[640 + p];
          gstf(&denwp[bid], tot);
        }
        float* big = smem + 1536;
#pragma unroll
        for (int i = 0; i < 8; ++i) big[wid * 512 + i * 64 + lane] = ae[i];
        __syncthreads();
#pragma unroll
        for (int st = 8; st; st >>= 1) {
          for (int i = tid; i < st * 512; i += NTHR) big[i] += big[i + st * 512];
          __syncthreads();
        }
        if (tid < 512) {
          int dim = ((tid & 63) << 3) | (tid >> 6);
          atomicAdd(&eanx8[(bid & 7) * EDIM + dim], big[tid]);
        }
      }
    }
    rnd++; gridbar(bar, bid, rnd);
  }
}

extern "C" void kernel_launch(void* const* d_in, const int* in_sizes, int n_in,
                              void* d_out, int out_size, void* d_ws, size_t ws_size,
                              hipStream_t stream) {
  const float* hidden  = (const float*)d_in[0];
  const float* emb_src = (const float*)d_in[1];
  const float* emb_T   = (const float*)d_in[2];
  const float* W_ih    = (const float*)d_in[3];
  const float* W_hh    = (const float*)d_in[4];
  const float* b_ih    = (const float*)d_in[5];
  const float* b_hh    = (const float*)d_in[6];
  const float* attn_W1 = (const float*)d_in[7];
  const float* attn_b1 = (const float*)d_in[8];
  const float* attn_v  = (const float*)d_in[9];
  const float* out_W   = (const float*)d_in[10];
  const float* out_b   = (const float*)d_in[11];
  float* out = (float*)d_out;
  char* wsb  = (char*)d_ws;

  hipMemsetAsync(wsb + OFF_BAR, 0, 18432, stream);

  void* args[] = {
    (void*)&hidden, (void*)&emb_src, (void*)&emb_T, (void*)&W_ih, (void*)&W_hh,
    (void*)&b_ih, (void*)&b_hh, (void*)&attn_W1, (void*)&attn_b1, (void*)&attn_v,
    (void*)&out_W, (void*)&out_b, (void*)&out, (void*)&wsb
  };
  hipLaunchCooperativeKernel((void*)k_decoder, dim3(NBLK), dim3(NTHR), args, 0, stream);
}